// Round 13
// baseline (579.046 us; speedup 1.0000x reference)
//
#include <hip/hip_runtime.h>
#include <cmath>

#define SEQ 2048
#define DDIM 1024
#define NROWS 8192   // B*S
#define KSEL 8
#define NCAND 12
#define IMAXC 0x7fffffff

typedef __attribute__((ext_vector_type(8))) short bf16x8;
typedef __attribute__((ext_vector_type(4))) float f32x4;
typedef __attribute__((ext_vector_type(4))) double f64x4;

__device__ __forceinline__ unsigned short f2bf(float f) {
  unsigned u = __builtin_bit_cast(unsigned, f);
  u = (u + 0x7fffu + ((u >> 16) & 1u)) >> 16;
  return (unsigned short)u;
}
__device__ __forceinline__ float bf2f(unsigned short h) {
  unsigned u = ((unsigned)h) << 16;
  return __builtin_bit_cast(float, u);
}
__device__ __forceinline__ unsigned pkbf(float a, float b) {
  unsigned r;
  asm("v_cvt_pk_bf16_f32 %0, %1, %2" : "=v"(r) : "v"(a), "v"(b));
  return r;
}
// D-fragment (row,col) within a 16x16 tile for f64 mfma, by probed layout sel
__device__ __forceinline__ void dmap(int sel, int lg, int lr, int rg,
                                     int& ri, int& ci) {
  switch (sel) {
    case 0:  ri = (lg << 2) + rg; ci = lr; break;
    case 1:  ri = lg + (rg << 2); ci = lr; break;
    case 2:  ri = lr; ci = (lg << 2) + rg; break;
    default: ri = lr; ci = lg + (rg << 2); break;
  }
}

// ---------------------------------------------------------------------------
// kprobe -- UNCHANGED
// ---------------------------------------------------------------------------
__global__ void kprobe(int* __restrict__ sel) {
  const int lane = threadIdx.x;
  const int lr = lane & 15, lg = lane >> 4;
  const double a = (double)(4 * lr + lg + 1);
  const double b = (double)(9 * lr + 5 * lg + 2);
  f64x4 d = (f64x4){0.0, 0.0, 0.0, 0.0};
  d = __builtin_amdgcn_mfma_f64_16x16x4f64(a, b, d, 0, 0, 0);
  int my = 4;
  for (int s = 3; s >= 0; --s) {
    bool ok = true;
    for (int rg = 0; rg < 4; ++rg) {
      int ri, ci;
      dmap(s, lg, lr, rg, ri, ci);
      double e = 0.0;
      for (int k = 0; k < 4; ++k)
        e += (double)(4 * ri + k + 1) * (double)(9 * ci + 5 * k + 2);
      ok = ok && (d[rg] == e);
    }
    if (__all(ok)) my = s;
  }
  if (lane == 0) sel[0] = my;
}

// ---------------------------------------------------------------------------
// k0_mfma -- UNCHANGED (R10)
// ---------------------------------------------------------------------------
#define K0_STAGE(bi)                                        \
  do {                                                      \
    *reinterpret_cast<float4*>(&As[bi][kr][c4]) = pa0;      \
    *reinterpret_cast<float4*>(&As[bi][kr][c4 + 32]) = pa1; \
    *reinterpret_cast<float4*>(&Bs[bi][kr][c4]) = pb0;      \
    *reinterpret_cast<float4*>(&Bs[bi][kr][c4 + 32]) = pb1; \
  } while (0)

__global__ __launch_bounds__(256, 2)
void k0_mfma(const float* __restrict__ A, const float* __restrict__ B,
             float* __restrict__ C, const int* __restrict__ selp) {
  const int sel = selp[0];
  if (sel >= 4) return;
  __shared__ float As[2][32][72];
  __shared__ float Bs[2][32][72];
  const int tid = threadIdx.x;
  const int lane = tid & 63, w = tid >> 6;
  const int wr = w >> 1, wc = w & 1;
  const int lr = lane & 15, lg = lane >> 4;
  const int brow = blockIdx.y << 6, bcol = blockIdx.x << 6;
  const int kr = tid >> 3, c4 = (tid & 7) << 2;

  f64x4 acc[2][2];
#pragma unroll
  for (int mi = 0; mi < 2; ++mi)
#pragma unroll
    for (int nj = 0; nj < 2; ++nj)
      acc[mi][nj] = (f64x4){0.0, 0.0, 0.0, 0.0};

  const float* Ap = &A[(size_t)kr * DDIM + brow + c4];
  const float* Bp = &B[(size_t)kr * DDIM + bcol + c4];
  float4 pa0 = *reinterpret_cast<const float4*>(Ap);
  float4 pa1 = *reinterpret_cast<const float4*>(Ap + 32);
  float4 pb0 = *reinterpret_cast<const float4*>(Bp);
  float4 pb1 = *reinterpret_cast<const float4*>(Bp + 32);
  K0_STAGE(0);
  {
    const size_t nk = (size_t)32 * DDIM;
    pa0 = *reinterpret_cast<const float4*>(Ap + nk);
    pa1 = *reinterpret_cast<const float4*>(Ap + nk + 32);
    pb0 = *reinterpret_cast<const float4*>(Bp + nk);
    pb1 = *reinterpret_cast<const float4*>(Bp + nk + 32);
  }

  for (int t = 0; t < 32; ++t) {
    __syncthreads();
    const int cur = t & 1;
    if (t < 31) {
      K0_STAGE(cur ^ 1);
      if (t < 30) {
        const size_t nk = (size_t)(t + 2) * 32 * DDIM;
        pa0 = *reinterpret_cast<const float4*>(Ap + nk);
        pa1 = *reinterpret_cast<const float4*>(Ap + nk + 32);
        pb0 = *reinterpret_cast<const float4*>(Bp + nk);
        pb1 = *reinterpret_cast<const float4*>(Bp + nk + 32);
      }
    }
    __builtin_amdgcn_s_setprio(1);
#pragma unroll
    for (int kp = 0; kp < 8; ++kp) {
      const int ka = (kp << 2) + lg;
      double a[2], b[2];
#pragma unroll
      for (int mi = 0; mi < 2; ++mi)
        a[mi] = (double)As[cur][ka][(wr << 5) + (mi << 4) + lr];
#pragma unroll
      for (int nj = 0; nj < 2; ++nj)
        b[nj] = (double)Bs[cur][ka][(wc << 5) + (nj << 4) + lr];
#pragma unroll
      for (int mi = 0; mi < 2; ++mi)
#pragma unroll
        for (int nj = 0; nj < 2; ++nj)
          acc[mi][nj] = __builtin_amdgcn_mfma_f64_16x16x4f64(
              a[mi], b[nj], acc[mi][nj], 0, 0, 0);
    }
    __builtin_amdgcn_s_setprio(0);
  }
#pragma unroll
  for (int mi = 0; mi < 2; ++mi)
#pragma unroll
    for (int nj = 0; nj < 2; ++nj)
#pragma unroll
      for (int rg = 0; rg < 4; ++rg) {
        int ri, ci;
        dmap(sel, lg, lr, rg, ri, ci);
        C[(size_t)(brow + (wr << 5) + (mi << 4) + ri) * DDIM +
          bcol + (wc << 5) + (nj << 4) + ci] = (float)acc[mi][nj][rg];
      }
}

// ---------------------------------------------------------------------------
// k0_repair -- UNCHANGED
// ---------------------------------------------------------------------------
__global__ __launch_bounds__(256)
void k0_repair(const float* __restrict__ A, const float* __restrict__ B,
               float* __restrict__ C, const int* __restrict__ selp) {
  if (selp[0] < 4) return;
  __shared__ __align__(16) float As[32][68];
  __shared__ __align__(16) float Bs[32][68];
  const int tid = threadIdx.x;
  const int tx = tid & 15, ty = tid >> 4;
  const int brow = blockIdx.y << 6;
  const int bcol = blockIdx.x << 6;
  double acc[4][4] = {};
  for (int k0 = 0; k0 < DDIM; k0 += 32) {
#pragma unroll
    for (int i = 0; i < 2; ++i) {
      const int f = tid + (i << 8);
      const int r = f >> 4;
      const int c4 = (f & 15) << 2;
      *reinterpret_cast<float4*>(&As[r][c4]) =
          *reinterpret_cast<const float4*>(&A[(size_t)(k0 + r) * DDIM + brow + c4]);
      *reinterpret_cast<float4*>(&Bs[r][c4]) =
          *reinterpret_cast<const float4*>(&B[(size_t)(k0 + r) * DDIM + bcol + c4]);
    }
    __syncthreads();
#pragma unroll
    for (int kk = 0; kk < 32; ++kk) {
      const float4 a = *reinterpret_cast<const float4*>(&As[kk][ty << 2]);
      const float4 b = *reinterpret_cast<const float4*>(&Bs[kk][tx << 2]);
      const double ad[4] = {a.x, a.y, a.z, a.w};
      const double bd[4] = {b.x, b.y, b.z, b.w};
#pragma unroll
      for (int i = 0; i < 4; ++i)
#pragma unroll
        for (int j = 0; j < 4; ++j)
          acc[i][j] = fma(ad[i], bd[j], acc[i][j]);
    }
    __syncthreads();
  }
#pragma unroll
  for (int i = 0; i < 4; ++i) {
    float4 v = make_float4((float)acc[i][0], (float)acc[i][1],
                           (float)acc[i][2], (float)acc[i][3]);
    *reinterpret_cast<float4*>(
        &C[(size_t)(brow + (ty << 2) + i) * DDIM + bcol + (tx << 2)]) = v;
  }
}

// ---------------------------------------------------------------------------
// k1_mfma: T = H * Wc (f64 MFMA, dbuf, setprio) + OPTIONAL fused Tb=bf16(T)
// store in the epilogue (Tb==nullptr -> skip; T itself bitwise-unchanged).
// ---------------------------------------------------------------------------
#define K1_STAGE(bi)                                              \
  do {                                                            \
    As[bi][akh + 0][ar] = pa0.x; As[bi][akh + 1][ar] = pa0.y;     \
    As[bi][akh + 2][ar] = pa0.z; As[bi][akh + 3][ar] = pa0.w;     \
    As[bi][akh + 4][ar] = pa1.x; As[bi][akh + 5][ar] = pa1.y;     \
    As[bi][akh + 6][ar] = pa1.z; As[bi][akh + 7][ar] = pa1.w;     \
    *reinterpret_cast<float4*>(&Bs[bi][bk][bc4]) = pb0;           \
    *reinterpret_cast<float4*>(&Bs[bi][bk][bc4 + 64]) = pb1;      \
  } while (0)

__global__ __launch_bounds__(256, 2)
void k1_mfma(const float* __restrict__ A, const float* __restrict__ B,
             float* __restrict__ C, unsigned short* __restrict__ Tb,
             const int* __restrict__ selp) {
  const int sel = selp[0];
  if (sel >= 4) return;
  __shared__ float As[2][16][144];
  __shared__ float Bs[2][16][144];
  const int tid = threadIdx.x;
  const int lin = blockIdx.y * 8 + blockIdx.x;
  const int nlin = (lin & 7) * 64 + (lin >> 3);
  const int brow = (nlin >> 3) << 7;
  const int bcol = (nlin & 7) << 7;
  const int lane = tid & 63, w = tid >> 6;
  const int wr = w >> 1, wc = w & 1;
  const int lr = lane & 15, lg = lane >> 4;
  const int ar = tid >> 1, akh = (tid & 1) << 3;
  const int bk = tid >> 4, bc4 = (tid & 15) << 2;

  f64x4 acc[4][4];
#pragma unroll
  for (int mi = 0; mi < 4; ++mi)
#pragma unroll
    for (int nj = 0; nj < 4; ++nj)
      acc[mi][nj] = (f64x4){0.0, 0.0, 0.0, 0.0};

  const float* Ap = &A[(size_t)(brow + ar) * DDIM + akh];
  const float* Bp = &B[(size_t)bk * DDIM + bcol + bc4];

  float4 pa0 = *reinterpret_cast<const float4*>(Ap);
  float4 pa1 = *reinterpret_cast<const float4*>(Ap + 4);
  float4 pb0 = *reinterpret_cast<const float4*>(Bp);
  float4 pb1 = *reinterpret_cast<const float4*>(Bp + 64);
  K1_STAGE(0);
  pa0 = *reinterpret_cast<const float4*>(Ap + 16);
  pa1 = *reinterpret_cast<const float4*>(Ap + 20);
  pb0 = *reinterpret_cast<const float4*>(Bp + (size_t)16 * DDIM);
  pb1 = *reinterpret_cast<const float4*>(Bp + (size_t)16 * DDIM + 64);

  for (int t = 0; t < 64; ++t) {
    __syncthreads();
    const int cur = t & 1;
    if (t < 63) {
      K1_STAGE(cur ^ 1);
      if (t < 62) {
        const size_t ko = (size_t)(t + 2) << 4;
        pa0 = *reinterpret_cast<const float4*>(Ap + ko);
        pa1 = *reinterpret_cast<const float4*>(Ap + ko + 4);
        pb0 = *reinterpret_cast<const float4*>(Bp + ko * DDIM);
        pb1 = *reinterpret_cast<const float4*>(Bp + ko * DDIM + 64);
      }
    }
    __builtin_amdgcn_s_setprio(1);
#pragma unroll
    for (int kp = 0; kp < 4; ++kp) {
      const int ka = (kp << 2) + lg;
      double a[4], b[4];
#pragma unroll
      for (int mi = 0; mi < 4; ++mi)
        a[mi] = (double)As[cur][ka][(wr << 6) + (mi << 4) + lr];
#pragma unroll
      for (int nj = 0; nj < 4; ++nj)
        b[nj] = (double)Bs[cur][ka][(wc << 6) + (nj << 4) + lr];
#pragma unroll
      for (int mi = 0; mi < 4; ++mi)
#pragma unroll
        for (int nj = 0; nj < 4; ++nj)
          acc[mi][nj] = __builtin_amdgcn_mfma_f64_16x16x4f64(
              a[mi], b[nj], acc[mi][nj], 0, 0, 0);
    }
    __builtin_amdgcn_s_setprio(0);
  }
  const bool wtb = (Tb != nullptr);
#pragma unroll
  for (int mi = 0; mi < 4; ++mi)
#pragma unroll
    for (int nj = 0; nj < 4; ++nj)
#pragma unroll
      for (int rg = 0; rg < 4; ++rg) {
        int ri, ci;
        dmap(sel, lg, lr, rg, ri, ci);
        const size_t idx = (size_t)(brow + (wr << 6) + (mi << 4) + ri) * DDIM +
                           bcol + (wc << 6) + (nj << 4) + ci;
        const float v = (float)acc[mi][nj][rg];
        C[idx] = v;
        if (wtb) Tb[idx] = f2bf(v);
      }
}

// ---------------------------------------------------------------------------
// k1_repair: proven vector-f64 chain; + optional fused Tb store.
// ---------------------------------------------------------------------------
__global__ __launch_bounds__(256, 2)
void k1_repair(const float* __restrict__ A, const float* __restrict__ B,
               float* __restrict__ C, unsigned short* __restrict__ Tb,
               const int* __restrict__ selp) {
  if (selp[0] < 4) return;
  __shared__ double As[128][17];
  __shared__ double Bs[16][130];
  const int tid = threadIdx.x;
  const int lin = blockIdx.y * 8 + blockIdx.x;
  const int nlin = (lin & 7) * 64 + (lin >> 3);
  const int brow = (nlin >> 3) << 7;
  const int bcol = (nlin & 7) << 7;
  const int tx = tid & 15, ty = tid >> 4;
  const int ar = tid >> 1, aks = (tid & 1) << 3;
  const int bk = tid >> 4, btx = tid & 15;

  double acc[8][8];
#pragma unroll
  for (int i = 0; i < 8; ++i)
#pragma unroll
    for (int j = 0; j < 8; ++j) acc[i][j] = 0.0;

  const float* Aptr = &A[(size_t)(brow + ar) * DDIM + aks];
  const float* Bptr = &B[(size_t)bk * DDIM + bcol + (btx << 1)];

  float4 pa0, pa1;
  float2 pb[4];
  pa0 = *reinterpret_cast<const float4*>(Aptr);
  pa1 = *reinterpret_cast<const float4*>(Aptr + 4);
#pragma unroll
  for (int w = 0; w < 4; ++w)
    pb[w] = *reinterpret_cast<const float2*>(Bptr + (w << 5));

  for (int k0 = 0; k0 < DDIM; k0 += 16) {
    __syncthreads();
    As[ar][aks + 0] = (double)pa0.x; As[ar][aks + 1] = (double)pa0.y;
    As[ar][aks + 2] = (double)pa0.z; As[ar][aks + 3] = (double)pa0.w;
    As[ar][aks + 4] = (double)pa1.x; As[ar][aks + 5] = (double)pa1.y;
    As[ar][aks + 6] = (double)pa1.z; As[ar][aks + 7] = (double)pa1.w;
#pragma unroll
    for (int w = 0; w < 4; ++w) {
      Bs[bk][(btx << 1) + (w << 5) + 0] = (double)pb[w].x;
      Bs[bk][(btx << 1) + (w << 5) + 1] = (double)pb[w].y;
    }
    __syncthreads();
    if (k0 + 16 < DDIM) {
      pa0 = *reinterpret_cast<const float4*>(Aptr + k0 + 16);
      pa1 = *reinterpret_cast<const float4*>(Aptr + k0 + 20);
#pragma unroll
      for (int w = 0; w < 4; ++w)
        pb[w] = *reinterpret_cast<const float2*>(
            Bptr + (size_t)(k0 + 16) * DDIM + (w << 5));
    }
#pragma unroll 8
    for (int kk = 0; kk < 16; ++kk) {
      double a[8];
      double2 b[4];
#pragma unroll
      for (int i = 0; i < 8; ++i) a[i] = As[(ty << 3) + i][kk];
#pragma unroll
      for (int jj = 0; jj < 4; ++jj)
        b[jj] = *reinterpret_cast<const double2*>(&Bs[kk][(tx << 1) + (jj << 5)]);
#pragma unroll
      for (int i = 0; i < 8; ++i) {
#pragma unroll
        for (int jj = 0; jj < 4; ++jj) {
          acc[i][(jj << 1) + 0] = fma(a[i], b[jj].x, acc[i][(jj << 1) + 0]);
          acc[i][(jj << 1) + 1] = fma(a[i], b[jj].y, acc[i][(jj << 1) + 1]);
        }
      }
    }
  }
  const bool wtb = (Tb != nullptr);
#pragma unroll
  for (int i = 0; i < 8; ++i) {
    const size_t rowi = (size_t)(brow + (ty << 3) + i);
    float* crow = &C[rowi * DDIM + bcol + (tx << 1)];
#pragma unroll
    for (int jj = 0; jj < 4; ++jj) {
      float2 v = make_float2((float)acc[i][(jj << 1)],
                             (float)acc[i][(jj << 1) + 1]);
      *reinterpret_cast<float2*>(crow + (jj << 5)) = v;
      if (wtb)
        *reinterpret_cast<unsigned*>(
            &Tb[rowi * DDIM + bcol + (tx << 1) + (jj << 5)]) = pkbf(v.x, v.y);
    }
  }
}

// ---------------------------------------------------------------------------
// kh: H (f32) -> Hb (bf16, RNE). 8 elems/thread.
// ---------------------------------------------------------------------------
__global__ __launch_bounds__(256)
void kh(const float* __restrict__ Hin, unsigned short* __restrict__ Hb) {
  const size_t i = ((size_t)blockIdx.x * 256 + threadIdx.x) << 3;
  const float4 a0 = *reinterpret_cast<const float4*>(&Hin[i]);
  const float4 a1 = *reinterpret_cast<const float4*>(&Hin[i + 4]);
  uint4 o;
  o.x = pkbf(a0.x, a0.y); o.y = pkbf(a0.z, a0.w);
  o.z = pkbf(a1.x, a1.y); o.w = pkbf(a1.z, a1.w);
  *reinterpret_cast<uint4*>(&Hb[i]) = o;
}

// ---------------------------------------------------------------------------
// k2_mfma_b: approx scores from PRE-CONVERTED bf16 Tb/Hb. 256x256 tile,
// 512 threads, dbuf staging = raw uint4 copies (no cvt, half the load
// bytes). LDS layout / swizzle / compute / epilogue identical to R12.
// ---------------------------------------------------------------------------
#define K2B_LOAD(koff)                                                        \
  do {                                                                        \
    _Pragma("unroll")                                                         \
    for (int q = 0; q < 4; ++q) {                                             \
      const int c = (q << 9) + tid;                                           \
      const int row = c >> 3;                                                 \
      const int gs = (c & 7) ^ (row & 7);                                     \
      rT[q] = *reinterpret_cast<const uint4*>(                                \
          &Tb[(size_t)(row0g + row) * DDIM + (koff) + (gs << 3)]);            \
      rH[q] = *reinterpret_cast<const uint4*>(                                \
          &Hb[(size_t)(col0g + row) * DDIM + (koff) + (gs << 3)]);            \
    }                                                                         \
  } while (0)

#define K2B_STAGE(bi)                                                         \
  do {                                                                        \
    _Pragma("unroll")                                                         \
    for (int q = 0; q < 4; ++q) {                                             \
      const int c = (q << 9) + tid;                                           \
      *reinterpret_cast<uint4*>(&u.stage[bi][0][c << 3]) = rT[q];             \
      *reinterpret_cast<uint4*>(&u.stage[bi][1][c << 3]) = rH[q];             \
    }                                                                         \
  } while (0)

__global__ __launch_bounds__(512, 1)
void k2_mfma_b(const unsigned short* __restrict__ Tb,
               const unsigned short* __restrict__ Hb,
               unsigned short* __restrict__ cand_v,
               unsigned char* __restrict__ cand_i) {
  __shared__ union {
    unsigned short stage[2][2][256 * 64];   // 128 KB
    float Sl[64][264];
    struct {
      float mv[512][8];
      unsigned char mi[512][8];
    } mg;
  } u;
  const int tid = threadIdx.x;
  const int lane = tid & 63;
  const int w = tid >> 6;
  const int wr = w >> 2, wc = w & 3;
  const int lr = lane & 15, lg = lane >> 4;
  const int z = blockIdx.z;
  const int bx = blockIdx.x;
  const int brow = blockIdx.y << 8, bcol = bx << 8;
  const int row0g = z * SEQ + brow;
  const int col0g = z * SEQ + bcol;

  f32x4 acc[8][4];
#pragma unroll
  for (int mi = 0; mi < 8; ++mi)
#pragma unroll
    for (int nj = 0; nj < 4; ++nj)
      acc[mi][nj] = (f32x4){0.f, 0.f, 0.f, 0.f};

  uint4 rT[4], rH[4];
  K2B_LOAD(0);
  K2B_STAGE(0);
  K2B_LOAD(64);

  for (int t = 0; t < 16; ++t) {
    __syncthreads();
    const int cur = t & 1;
    if (t < 15) {
      K2B_STAGE(cur ^ 1);
      if (t < 14) K2B_LOAD((t + 2) << 6);
    }
#pragma unroll
    for (int kh2 = 0; kh2 < 2; ++kh2) {
      const int sl = (kh2 << 2) + lg;
      bf16x8 bfv[4];
#pragma unroll
      for (int nj = 0; nj < 4; ++nj) {
        const int rb = (wc << 6) + (nj << 4) + lr;
        bfv[nj] = *reinterpret_cast<const bf16x8*>(
            &u.stage[cur][1][(rb << 6) + ((sl ^ (rb & 7)) << 3)]);
      }
#pragma unroll
      for (int mi = 0; mi < 8; ++mi) {
        const int ra = (wr << 7) + (mi << 4) + lr;
        const bf16x8 af = *reinterpret_cast<const bf16x8*>(
            &u.stage[cur][0][(ra << 6) + ((sl ^ (ra & 7)) << 3)]);
#pragma unroll
        for (int nj = 0; nj < 4; ++nj)
          acc[mi][nj] = __builtin_amdgcn_mfma_f32_16x16x32_bf16(
              af, bfv[nj], acc[mi][nj], 0, 0, 0);
      }
    }
  }

  const int srow = tid >> 3;
  const int qd = tid & 7;
#pragma unroll
  for (int p = 0; p < 4; ++p) {
    __syncthreads();
    if (wr == (p >> 1)) {
      const int mib = (p & 1) << 2;
#pragma unroll
      for (int mi2 = 0; mi2 < 4; ++mi2)
#pragma unroll
        for (int nj = 0; nj < 4; ++nj)
#pragma unroll
          for (int rg = 0; rg < 4; ++rg)
            u.Sl[(mi2 << 4) + (lg << 2) + rg][(wc << 6) + (nj << 4) + lr] =
                acc[mib + mi2][nj][rg];
    }
    __syncthreads();
    float v[KSEL];
    int ci[KSEL];
#pragma unroll
    for (int s = 0; s < KSEL; ++s) { v[s] = -3.0e38f; ci[s] = 0; }
    const int c0 = qd << 5;
    for (int c = 0; c < 32; ++c) {
      const float x = u.Sl[srow][c0 + c];
      if (x > v[KSEL - 1]) {
        float pv = x; int pc = c0 + c;
#pragma unroll
        for (int s = 0; s < KSEL; ++s) {
          if (x > v[s]) {
            const float tv = v[s]; const int tc = ci[s];
            v[s] = pv; ci[s] = pc; pv = tv; pc = tc;
          }
        }
      }
    }
    __syncthreads();
#pragma unroll
    for (int s = 0; s < KSEL; ++s) {
      u.mg.mv[tid][s] = v[s];
      u.mg.mi[tid][s] = (unsigned char)ci[s];
    }
    __syncthreads();
    if (qd == 0) {
      float fv[KSEL];
      int fi[KSEL];
#pragma unroll
      for (int s = 0; s < KSEL; ++s) { fv[s] = -3.0e38f; fi[s] = 0; }
#pragma unroll
      for (int t2 = 0; t2 < 8; ++t2) {
#pragma unroll
        for (int s = 0; s < KSEL; ++s) {
          const float x = u.mg.mv[tid + t2][s];
          const int idx = u.mg.mi[tid + t2][s];
          if (x > fv[KSEL - 1]) {
            float pv = x; int pc = idx;
#pragma unroll
            for (int s2 = 0; s2 < KSEL; ++s2) {
              if (x > fv[s2]) {
                const float tv = fv[s2]; const int tc = fi[s2];
                fv[s2] = pv; fi[s2] = pc; pv = tv; pc = tc;
              }
            }
          }
        }
      }
      const size_t base =
          (size_t)(row0g + (p << 6) + srow) * 64 + ((size_t)bx << 3);
#pragma unroll
      for (int s = 0; s < KSEL; ++s) {
        cand_v[base + s] = f2bf(fv[s]);
        cand_i[base + s] = (unsigned char)fi[s];
      }
    }
  }
}

// ---------------------------------------------------------------------------
// k2_mfma: f32-input version (pkbf in staging) -- FALLBACK, UNCHANGED (R12)
// ---------------------------------------------------------------------------
#define K2_LOAD(koff)                                                         \
  do {                                                                        \
    _Pragma("unroll")                                                         \
    for (int q = 0; q < 4; ++q) {                                             \
      const int c = (q << 9) + tid;                                           \
      const int row = c >> 3;                                                 \
      const int gs = (c & 7) ^ (row & 7);                                     \
      const float* sT = &T[(size_t)(row0g + row) * DDIM + (koff) + (gs << 3)];\
      rT[2 * q] = *reinterpret_cast<const float4*>(sT);                       \
      rT[2 * q + 1] = *reinterpret_cast<const float4*>(sT + 4);               \
      const float* sH = &H[(size_t)(col0g + row) * DDIM + (koff) + (gs << 3)];\
      rH[2 * q] = *reinterpret_cast<const float4*>(sH);                       \
      rH[2 * q + 1] = *reinterpret_cast<const float4*>(sH + 4);               \
    }                                                                         \
  } while (0)

#define K2_STAGE(bi)                                                          \
  do {                                                                        \
    _Pragma("unroll")                                                         \
    for (int q = 0; q < 4; ++q) {                                             \
      const int c = (q << 9) + tid;                                           \
      uint4 o;                                                                \
      o.x = pkbf(rT[2 * q].x, rT[2 * q].y);                                   \
      o.y = pkbf(rT[2 * q].z, rT[2 * q].w);                                   \
      o.z = pkbf(rT[2 * q + 1].x, rT[2 * q + 1].y);                           \
      o.w = pkbf(rT[2 * q + 1].z, rT[2 * q + 1].w);                           \
      *reinterpret_cast<uint4*>(&u.stage[bi][0][c << 3]) = o;                 \
      uint4 o2;                                                               \
      o2.x = pkbf(rH[2 * q].x, rH[2 * q].y);                                  \
      o2.y = pkbf(rH[2 * q].z, rH[2 * q].w);                                  \
      o2.z = pkbf(rH[2 * q + 1].x, rH[2 * q + 1].y);                          \
      o2.w = pkbf(rH[2 * q + 1].z, rH[2 * q + 1].w);                          \
      *reinterpret_cast<uint4*>(&u.stage[bi][1][c << 3]) = o2;                \
    }                                                                         \
  } while (0)

__global__ __launch_bounds__(512, 1)
void k2_mfma(const float* __restrict__ T, const float* __restrict__ H,
             unsigned short* __restrict__ cand_v,
             unsigned char* __restrict__ cand_i) {
  __shared__ union {
    unsigned short stage[2][2][256 * 64];
    float Sl[64][264];
    struct {
      float mv[512][8];
      unsigned char mi[512][8];
    } mg;
  } u;
  const int tid = threadIdx.x;
  const int lane = tid & 63;
  const int w = tid >> 6;
  const int wr = w >> 2, wc = w & 3;
  const int lr = lane & 15, lg = lane >> 4;
  const int z = blockIdx.z;
  const int bx = blockIdx.x;
  const int brow = blockIdx.y << 8, bcol = bx << 8;
  const int row0g = z * SEQ + brow;
  const int col0g = z * SEQ + bcol;

  f32x4 acc[8][4];
#pragma unroll
  for (int mi = 0; mi < 8; ++mi)
#pragma unroll
    for (int nj = 0; nj < 4; ++nj)
      acc[mi][nj] = (f32x4){0.f, 0.f, 0.f, 0.f};

  float4 rT[8], rH[8];
  K2_LOAD(0);
  K2_STAGE(0);
  K2_LOAD(64);

  for (int t = 0; t < 16; ++t) {
    __syncthreads();
    const int cur = t & 1;
    if (t < 15) {
      K2_STAGE(cur ^ 1);
      if (t < 14) K2_LOAD((t + 2) << 6);
    }
#pragma unroll
    for (int kh2 = 0; kh2 < 2; ++kh2) {
      const int sl = (kh2 << 2) + lg;
      bf16x8 bfv[4];
#pragma unroll
      for (int nj = 0; nj < 4; ++nj) {
        const int rb = (wc << 6) + (nj << 4) + lr;
        bfv[nj] = *reinterpret_cast<const bf16x8*>(
            &u.stage[cur][1][(rb << 6) + ((sl ^ (rb & 7)) << 3)]);
      }
#pragma unroll
      for (int mi = 0; mi < 8; ++mi) {
        const int ra = (wr << 7) + (mi << 4) + lr;
        const bf16x8 af = *reinterpret_cast<const bf16x8*>(
            &u.stage[cur][0][(ra << 6) + ((sl ^ (ra & 7)) << 3)]);
#pragma unroll
        for (int nj = 0; nj < 4; ++nj)
          acc[mi][nj] = __builtin_amdgcn_mfma_f32_16x16x32_bf16(
              af, bfv[nj], acc[mi][nj], 0, 0, 0);
      }
    }
  }

  const int srow = tid >> 3;
  const int qd = tid & 7;
#pragma unroll
  for (int p = 0; p < 4; ++p) {
    __syncthreads();
    if (wr == (p >> 1)) {
      const int mib = (p & 1) << 2;
#pragma unroll
      for (int mi2 = 0; mi2 < 4; ++mi2)
#pragma unroll
        for (int nj = 0; nj < 4; ++nj)
#pragma unroll
          for (int rg = 0; rg < 4; ++rg)
            u.Sl[(mi2 << 4) + (lg << 2) + rg][(wc << 6) + (nj << 4) + lr] =
                acc[mib + mi2][nj][rg];
    }
    __syncthreads();
    float v[KSEL];
    int ci[KSEL];
#pragma unroll
    for (int s = 0; s < KSEL; ++s) { v[s] = -3.0e38f; ci[s] = 0; }
    const int c0 = qd << 5;
    for (int c = 0; c < 32; ++c) {
      const float x = u.Sl[srow][c0 + c];
      if (x > v[KSEL - 1]) {
        float pv = x; int pc = c0 + c;
#pragma unroll
        for (int s = 0; s < KSEL; ++s) {
          if (x > v[s]) {
            const float tv = v[s]; const int tc = ci[s];
            v[s] = pv; ci[s] = pc; pv = tv; pc = tc;
          }
        }
      }
    }
    __syncthreads();
#pragma unroll
    for (int s = 0; s < KSEL; ++s) {
      u.mg.mv[tid][s] = v[s];
      u.mg.mi[tid][s] = (unsigned char)ci[s];
    }
    __syncthreads();
    if (qd == 0) {
      float fv[KSEL];
      int fi[KSEL];
#pragma unroll
      for (int s = 0; s < KSEL; ++s) { fv[s] = -3.0e38f; fi[s] = 0; }
#pragma unroll
      for (int t2 = 0; t2 < 8; ++t2) {
#pragma unroll
        for (int s = 0; s < KSEL; ++s) {
          const float x = u.mg.mv[tid + t2][s];
          const int idx = u.mg.mi[tid + t2][s];
          if (x > fv[KSEL - 1]) {
            float pv = x; int pc = idx;
#pragma unroll
            for (int s2 = 0; s2 < KSEL; ++s2) {
              if (x > fv[s2]) {
                const float tv = fv[s2]; const int tc = fi[s2];
                fv[s2] = pv; fi[s2] = pc; pv = tv; pc = tc;
              }
            }
          }
        }
      }
      const size_t base =
          (size_t)(row0g + (p << 6) + srow) * 64 + ((size_t)bx << 3);
#pragma unroll
      for (int s = 0; s < KSEL; ++s) {
        cand_v[base + s] = f2bf(fv[s]);
        cand_i[base + s] = (unsigned char)fi[s];
      }
    }
  }
}

// ---------------------------------------------------------------------------
// kr_rescore -- UNCHANGED (R12: 2 rows/block, 2 waves/row, NCAND=12)
// ---------------------------------------------------------------------------
__global__ __launch_bounds__(256)
void kr_rescore(const float* __restrict__ T, const float* __restrict__ H,
                const unsigned short* __restrict__ cand_v,
                const unsigned char* __restrict__ cand_i,
                int* __restrict__ topi, float* __restrict__ topw,
                int* __restrict__ cnt) {
  __shared__ float smv[2][2][KSEL];
  __shared__ int smi[2][2][KSEL];
  const int tid = threadIdx.x, lane = tid & 63, w = tid >> 6;
  const int rl = w >> 1;
  const int half = w & 1;
  const int r = blockIdx.x * 2 + rl;
  const int b = r >> 11, iloc = r & (SEQ - 1);

  const size_t cbase = (size_t)r * 64;
  float v0 = bf2f(cand_v[cbase + lane]);
  int i0 = ((lane >> 3) << 8) + cand_i[cbase + lane];
  int keep = 0;
  for (int rnd = 0; rnd < NCAND; ++rnd) {
    float m = v0;
#pragma unroll
    for (int off = 32; off >= 1; off >>= 1) m = fmaxf(m, __shfl_xor(m, off));
    const unsigned long long bm = __ballot(v0 == m);
    const int owner = __ffsll(bm) - 1;
    const int oi = __shfl(i0, owner);
    if (lane == owner) v0 = -3.0e38f;
    if (lane == rnd) keep = oi;
  }

  const float* Trow = T + (size_t)r * DDIM;
  float4 t4[4];
#pragma unroll
  for (int q = 0; q < 4; ++q)
    t4[q] = *reinterpret_cast<const float4*>(&Trow[(q << 8) + (lane << 2)]);

  float t8v[KSEL];
  int t8i[KSEL];
#pragma unroll
  for (int p = 0; p < KSEL; ++p) { t8v[p] = -1.0f; t8i[p] = IMAXC; }

  const int c0 = half * (NCAND / 2);
  for (int c = c0; c < c0 + NCAND / 2; ++c) {
    const int j = __shfl(keep, c);
    const float* Hrow = H + ((size_t)(b << 11) + j) * DDIM;
    double s = 0.0;
#pragma unroll
    for (int q = 0; q < 4; ++q) {
      const float4 h = *reinterpret_cast<const float4*>(&Hrow[(q << 8) + (lane << 2)]);
      s = fma((double)t4[q].x, (double)h.x, s);
      s = fma((double)t4[q].y, (double)h.y, s);
      s = fma((double)t4[q].z, (double)h.z, s);
      s = fma((double)t4[q].w, (double)h.w, s);
    }
#pragma unroll
    for (int off = 1; off < 64; off <<= 1) s += __shfl_xor(s, off);
    const float aff = expf((float)s);
    const bool g7 = (aff > t8v[KSEL - 1]) ||
                    (aff == t8v[KSEL - 1] && j < t8i[KSEL - 1]);
    if (g7) {
      float pv = aff; int pi = j;
#pragma unroll
      for (int p = 0; p < KSEL; ++p) {
        const bool g = (aff > t8v[p]) || (aff == t8v[p] && j < t8i[p]);
        if (g) {
          const float tv = t8v[p]; const int ti = t8i[p];
          t8v[p] = pv; t8i[p] = pi; pv = tv; pi = ti;
        }
      }
    }
  }

  if (lane == 0) {
#pragma unroll
    for (int p = 0; p < KSEL; ++p) {
      smv[rl][half][p] = t8v[p];
      smi[rl][half][p] = t8i[p];
    }
  }
  __syncthreads();
  if (half == 0 && lane == 0) {
#pragma unroll
    for (int p = 0; p < KSEL; ++p) {
      const float x = smv[rl][1][p];
      const int jx = smi[rl][1][p];
      const bool g7 = (x > t8v[KSEL - 1]) ||
                      (x == t8v[KSEL - 1] && jx < t8i[KSEL - 1]);
      if (g7) {
        float pv = x; int pi = jx;
#pragma unroll
        for (int q = 0; q < KSEL; ++q) {
          const bool g = (x > t8v[q]) || (x == t8v[q] && jx < t8i[q]);
          if (g) {
            const float tv = t8v[q]; const int ti = t8i[q];
            t8v[q] = pv; t8i[q] = pi; pv = tv; pi = ti;
          }
        }
      }
    }
    float sum = 0.0f;
#pragma unroll
    for (int p = 0; p < KSEL; ++p) sum += t8v[p];
    sum += 1e-8f;
    int c8 = KSEL;
#pragma unroll
    for (int p = 0; p < KSEL; ++p)
      if (t8i[p] == iloc) --c8;
    cnt[r] = c8;
#pragma unroll
    for (int p = 0; p < KSEL; ++p) {
      topi[(size_t)r * KSEL + p] = t8i[p];
      topw[(size_t)r * KSEL + p] = t8v[p] / sum;
    }
  }
}

// ---------------------------------------------------------------------------
// k4_scan / k5_emit -- UNCHANGED
// ---------------------------------------------------------------------------
__global__ __launch_bounds__(1024)
void k4_scan(const int* __restrict__ cnt, int* __restrict__ off) {
  __shared__ int part[1024];
  const int t = threadIdx.x;
  int loc[8];
  int s = 0;
#pragma unroll
  for (int i = 0; i < 8; ++i) { loc[i] = s; s += cnt[t * 8 + i]; }
  part[t] = s;
  __syncthreads();
  for (int d = 1; d < 1024; d <<= 1) {
    const int add = (t >= d) ? part[t - d] : 0;
    __syncthreads();
    part[t] += add;
    __syncthreads();
  }
  const int base = (t == 0) ? 0 : part[t - 1];
#pragma unroll
  for (int i = 0; i < 8; ++i) off[t * 8 + i] = base + loc[i];
}

__global__ __launch_bounds__(256)
void k5_emit(const int* __restrict__ topi, const float* __restrict__ topw,
             const int* __restrict__ off, float* __restrict__ out, int E) {
  const int r = blockIdx.x * 256 + threadIdx.x;
  if (r >= NROWS) return;
  const int o = off[r];
  const int sloc = r & (SEQ - 1);
  const int bbase = r & ~(SEQ - 1);
  int e = 0;
#pragma unroll
  for (int p = 0; p < KSEL; ++p) {
    const int id = topi[(size_t)r * KSEL + p];
    const float w = topw[(size_t)r * KSEL + p];
    if (id != sloc) {
      const int pos = o + e;
      if (pos < E) {
        out[pos] = (float)r;
        out[(size_t)E + pos] = (float)(bbase + id);
        out[2 * (size_t)E + pos] = w;
      }
      ++e;
    }
  }
}

// ---------------------------------------------------------------------------
extern "C" void kernel_launch(void* const* d_in, const int* in_sizes, int n_in,
                              void* d_out, int out_size, void* d_ws,
                              size_t ws_size, hipStream_t stream) {
  const float* H = (const float*)d_in[0];      // [4,2048,1024]
  const float* Wphi = (const float*)d_in[1];   // [1024,1024]
  const float* Wpsi = (const float*)d_in[2];   // [1024,1024]
  float* out = (float*)d_out;
  const int E = out_size / 3;

  char* base = (char*)d_ws;
  float* T = (float*)base;                         // 32 MB
  char* regionX = base + 33554432;                 // 4 MB shared region
  float* Wc = (float*)regionX;                     //   Wc (dead after k1)
  unsigned short* cand_v = (unsigned short*)regionX;           // 1 MB used
  unsigned char* cand_i = (unsigned char*)(regionX + 2097152); // 0.5 MB used
  char* pp = regionX + 4194304;
  int* topi = (int*)pp;  pp += 262144;
  float* topw = (float*)pp; pp += 262144;
  int* cnt = (int*)pp;   pp += 32768;
  int* off = (int*)pp;   pp += 32768;
  int* sel = (int*)pp;

  // fast path extras: Tb @ 37 MiB (16 MiB), Hb @ 53 MiB (16 MiB)
  const size_t NEED_FAST = 72351744;
  const bool fast = (ws_size >= NEED_FAST);
  unsigned short* Tb = (unsigned short*)(base + 38797312);
  unsigned short* Hb = (unsigned short*)(base + 55574528);

  kprobe<<<dim3(1), 64, 0, stream>>>(sel);
  k0_mfma<<<dim3(16, 16), 256, 0, stream>>>(Wphi, Wpsi, Wc, sel);
  k0_repair<<<dim3(16, 16), 256, 0, stream>>>(Wphi, Wpsi, Wc, sel);

  if (fast) {
    k1_mfma<<<dim3(8, 64), 256, 0, stream>>>(H, Wc, T, Tb, sel);
    k1_repair<<<dim3(8, 64), 256, 0, stream>>>(H, Wc, T, Tb, sel);
    kh<<<dim3(4096), 256, 0, stream>>>(H, Hb);
    k2_mfma_b<<<dim3(8, 8, 4), 512, 0, stream>>>(Tb, Hb, cand_v, cand_i);
  } else {
    k1_mfma<<<dim3(8, 64), 256, 0, stream>>>(H, Wc, T, nullptr, sel);
    k1_repair<<<dim3(8, 64), 256, 0, stream>>>(H, Wc, T, nullptr, sel);
    k2_mfma<<<dim3(8, 8, 4), 512, 0, stream>>>(T, H, cand_v, cand_i);
  }
  kr_rescore<<<dim3(NROWS / 2), 256, 0, stream>>>(T, H, cand_v, cand_i,
                                                  topi, topw, cnt);
  k4_scan<<<dim3(1), 1024, 0, stream>>>(cnt, off);
  k5_emit<<<dim3(NROWS / 256), 256, 0, stream>>>(topi, topw, off, out, E);
}

// Round 14
// 553.128 us; speedup vs baseline: 1.0469x; 1.0469x over previous
//
#include <hip/hip_runtime.h>
#include <cmath>

#define SEQ 2048
#define DDIM 1024
#define NROWS 8192   // B*S
#define KSEL 8
#define NCAND 12
#define IMAXC 0x7fffffff

typedef __attribute__((ext_vector_type(8))) short bf16x8;
typedef __attribute__((ext_vector_type(4))) float f32x4;
typedef __attribute__((ext_vector_type(4))) double f64x4;

__device__ __forceinline__ unsigned short f2bf(float f) {
  unsigned u = __builtin_bit_cast(unsigned, f);
  u = (u + 0x7fffu + ((u >> 16) & 1u)) >> 16;
  return (unsigned short)u;
}
__device__ __forceinline__ float bf2f(unsigned short h) {
  unsigned u = ((unsigned)h) << 16;
  return __builtin_bit_cast(float, u);
}
__device__ __forceinline__ unsigned pkbf(float a, float b) {
  unsigned r;
  asm("v_cvt_pk_bf16_f32 %0, %1, %2" : "=v"(r) : "v"(a), "v"(b));
  return r;
}
// D-fragment (row,col) within a 16x16 tile for f64 mfma, by probed layout sel
__device__ __forceinline__ void dmap(int sel, int lg, int lr, int rg,
                                     int& ri, int& ci) {
  switch (sel) {
    case 0:  ri = (lg << 2) + rg; ci = lr; break;
    case 1:  ri = lg + (rg << 2); ci = lr; break;
    case 2:  ri = lr; ci = (lg << 2) + rg; break;
    default: ri = lr; ci = lg + (rg << 2); break;
  }
}

// ---------------------------------------------------------------------------
// kprobe: one wave determines the f64-MFMA D layout (exact integer check).
// sel=4 -> unknown -> vector repair kernels take over. -- UNCHANGED
// ---------------------------------------------------------------------------
__global__ void kprobe(int* __restrict__ sel) {
  const int lane = threadIdx.x;
  const int lr = lane & 15, lg = lane >> 4;
  const double a = (double)(4 * lr + lg + 1);
  const double b = (double)(9 * lr + 5 * lg + 2);
  f64x4 d = (f64x4){0.0, 0.0, 0.0, 0.0};
  d = __builtin_amdgcn_mfma_f64_16x16x4f64(a, b, d, 0, 0, 0);
  int my = 4;
  for (int s = 3; s >= 0; --s) {
    bool ok = true;
    for (int rg = 0; rg < 4; ++rg) {
      int ri, ci;
      dmap(s, lg, lr, rg, ri, ci);
      double e = 0.0;
      for (int k = 0; k < 4; ++k)
        e += (double)(4 * ri + k + 1) * (double)(9 * ci + 5 * k + 2);
      ok = ok && (d[rg] == e);
    }
    if (__all(ok)) my = s;
  }
  if (lane == 0) sel[0] = my;
}

// ---------------------------------------------------------------------------
// k0_mfma: Wc = Wphi^T * Wpsi (TN, f64 MFMA), dbuf, 1 barrier/step. -- UNCHANGED
// ---------------------------------------------------------------------------
#define K0_STAGE(bi)                                        \
  do {                                                      \
    *reinterpret_cast<float4*>(&As[bi][kr][c4]) = pa0;      \
    *reinterpret_cast<float4*>(&As[bi][kr][c4 + 32]) = pa1; \
    *reinterpret_cast<float4*>(&Bs[bi][kr][c4]) = pb0;      \
    *reinterpret_cast<float4*>(&Bs[bi][kr][c4 + 32]) = pb1; \
  } while (0)

__global__ __launch_bounds__(256, 2)
void k0_mfma(const float* __restrict__ A, const float* __restrict__ B,
             float* __restrict__ C, const int* __restrict__ selp) {
  const int sel = selp[0];
  if (sel >= 4) return;
  __shared__ float As[2][32][72];
  __shared__ float Bs[2][32][72];
  const int tid = threadIdx.x;
  const int lane = tid & 63, w = tid >> 6;
  const int wr = w >> 1, wc = w & 1;
  const int lr = lane & 15, lg = lane >> 4;
  const int brow = blockIdx.y << 6, bcol = blockIdx.x << 6;
  const int kr = tid >> 3, c4 = (tid & 7) << 2;

  f64x4 acc[2][2];
#pragma unroll
  for (int mi = 0; mi < 2; ++mi)
#pragma unroll
    for (int nj = 0; nj < 2; ++nj)
      acc[mi][nj] = (f64x4){0.0, 0.0, 0.0, 0.0};

  const float* Ap = &A[(size_t)kr * DDIM + brow + c4];
  const float* Bp = &B[(size_t)kr * DDIM + bcol + c4];
  float4 pa0 = *reinterpret_cast<const float4*>(Ap);
  float4 pa1 = *reinterpret_cast<const float4*>(Ap + 32);
  float4 pb0 = *reinterpret_cast<const float4*>(Bp);
  float4 pb1 = *reinterpret_cast<const float4*>(Bp + 32);
  K0_STAGE(0);
  {
    const size_t nk = (size_t)32 * DDIM;
    pa0 = *reinterpret_cast<const float4*>(Ap + nk);
    pa1 = *reinterpret_cast<const float4*>(Ap + nk + 32);
    pb0 = *reinterpret_cast<const float4*>(Bp + nk);
    pb1 = *reinterpret_cast<const float4*>(Bp + nk + 32);
  }

  for (int t = 0; t < 32; ++t) {
    __syncthreads();
    const int cur = t & 1;
    if (t < 31) {
      K0_STAGE(cur ^ 1);
      if (t < 30) {
        const size_t nk = (size_t)(t + 2) * 32 * DDIM;
        pa0 = *reinterpret_cast<const float4*>(Ap + nk);
        pa1 = *reinterpret_cast<const float4*>(Ap + nk + 32);
        pb0 = *reinterpret_cast<const float4*>(Bp + nk);
        pb1 = *reinterpret_cast<const float4*>(Bp + nk + 32);
      }
    }
    __builtin_amdgcn_s_setprio(1);
#pragma unroll
    for (int kp = 0; kp < 8; ++kp) {
      const int ka = (kp << 2) + lg;
      double a[2], b[2];
#pragma unroll
      for (int mi = 0; mi < 2; ++mi)
        a[mi] = (double)As[cur][ka][(wr << 5) + (mi << 4) + lr];
#pragma unroll
      for (int nj = 0; nj < 2; ++nj)
        b[nj] = (double)Bs[cur][ka][(wc << 5) + (nj << 4) + lr];
#pragma unroll
      for (int mi = 0; mi < 2; ++mi)
#pragma unroll
        for (int nj = 0; nj < 2; ++nj)
          acc[mi][nj] = __builtin_amdgcn_mfma_f64_16x16x4f64(
              a[mi], b[nj], acc[mi][nj], 0, 0, 0);
    }
    __builtin_amdgcn_s_setprio(0);
  }
#pragma unroll
  for (int mi = 0; mi < 2; ++mi)
#pragma unroll
    for (int nj = 0; nj < 2; ++nj)
#pragma unroll
      for (int rg = 0; rg < 4; ++rg) {
        int ri, ci;
        dmap(sel, lg, lr, rg, ri, ci);
        C[(size_t)(brow + (wr << 5) + (mi << 4) + ri) * DDIM +
          bcol + (wc << 5) + (nj << 4) + ci] = (float)acc[mi][nj][rg];
      }
}

// ---------------------------------------------------------------------------
// k0_repair: proven vector-f64 TN kernel; runs only if sel unknown. -- UNCHANGED
// ---------------------------------------------------------------------------
__global__ __launch_bounds__(256)
void k0_repair(const float* __restrict__ A, const float* __restrict__ B,
               float* __restrict__ C, const int* __restrict__ selp) {
  if (selp[0] < 4) return;
  __shared__ __align__(16) float As[32][68];
  __shared__ __align__(16) float Bs[32][68];
  const int tid = threadIdx.x;
  const int tx = tid & 15, ty = tid >> 4;
  const int brow = blockIdx.y << 6;
  const int bcol = blockIdx.x << 6;
  double acc[4][4] = {};
  for (int k0 = 0; k0 < DDIM; k0 += 32) {
#pragma unroll
    for (int i = 0; i < 2; ++i) {
      const int f = tid + (i << 8);
      const int r = f >> 4;
      const int c4 = (f & 15) << 2;
      *reinterpret_cast<float4*>(&As[r][c4]) =
          *reinterpret_cast<const float4*>(&A[(size_t)(k0 + r) * DDIM + brow + c4]);
      *reinterpret_cast<float4*>(&Bs[r][c4]) =
          *reinterpret_cast<const float4*>(&B[(size_t)(k0 + r) * DDIM + bcol + c4]);
    }
    __syncthreads();
#pragma unroll
    for (int kk = 0; kk < 32; ++kk) {
      const float4 a = *reinterpret_cast<const float4*>(&As[kk][ty << 2]);
      const float4 b = *reinterpret_cast<const float4*>(&Bs[kk][tx << 2]);
      const double ad[4] = {a.x, a.y, a.z, a.w};
      const double bd[4] = {b.x, b.y, b.z, b.w};
#pragma unroll
      for (int i = 0; i < 4; ++i)
#pragma unroll
        for (int j = 0; j < 4; ++j)
          acc[i][j] = fma(ad[i], bd[j], acc[i][j]);
    }
    __syncthreads();
  }
#pragma unroll
  for (int i = 0; i < 4; ++i) {
    float4 v = make_float4((float)acc[i][0], (float)acc[i][1],
                           (float)acc[i][2], (float)acc[i][3]);
    *reinterpret_cast<float4*>(
        &C[(size_t)(brow + (ty << 2) + i) * DDIM + bcol + (tx << 2)]) = v;
  }
}

// ---------------------------------------------------------------------------
// k1_mfma: T = H * Wc (NN, f64 MFMA), dbuf, 1 barrier/K-step, setprio.
// -- UNCHANGED (R10/R12 proven: 287 us, MfmaUtil ~80%)
// ---------------------------------------------------------------------------
#define K1_STAGE(bi)                                              \
  do {                                                            \
    As[bi][akh + 0][ar] = pa0.x; As[bi][akh + 1][ar] = pa0.y;     \
    As[bi][akh + 2][ar] = pa0.z; As[bi][akh + 3][ar] = pa0.w;     \
    As[bi][akh + 4][ar] = pa1.x; As[bi][akh + 5][ar] = pa1.y;     \
    As[bi][akh + 6][ar] = pa1.z; As[bi][akh + 7][ar] = pa1.w;     \
    *reinterpret_cast<float4*>(&Bs[bi][bk][bc4]) = pb0;           \
    *reinterpret_cast<float4*>(&Bs[bi][bk][bc4 + 64]) = pb1;      \
  } while (0)

__global__ __launch_bounds__(256, 2)
void k1_mfma(const float* __restrict__ A, const float* __restrict__ B,
             float* __restrict__ C, const int* __restrict__ selp) {
  const int sel = selp[0];
  if (sel >= 4) return;
  __shared__ float As[2][16][144];
  __shared__ float Bs[2][16][144];
  const int tid = threadIdx.x;
  const int lin = blockIdx.y * 8 + blockIdx.x;          // 512 blocks
  const int nlin = (lin & 7) * 64 + (lin >> 3);         // bijective XCD swizzle
  const int brow = (nlin >> 3) << 7;
  const int bcol = (nlin & 7) << 7;
  const int lane = tid & 63, w = tid >> 6;
  const int wr = w >> 1, wc = w & 1;
  const int lr = lane & 15, lg = lane >> 4;
  const int ar = tid >> 1, akh = (tid & 1) << 3;
  const int bk = tid >> 4, bc4 = (tid & 15) << 2;

  f64x4 acc[4][4];
#pragma unroll
  for (int mi = 0; mi < 4; ++mi)
#pragma unroll
    for (int nj = 0; nj < 4; ++nj)
      acc[mi][nj] = (f64x4){0.0, 0.0, 0.0, 0.0};

  const float* Ap = &A[(size_t)(brow + ar) * DDIM + akh];
  const float* Bp = &B[(size_t)bk * DDIM + bcol + bc4];

  float4 pa0 = *reinterpret_cast<const float4*>(Ap);
  float4 pa1 = *reinterpret_cast<const float4*>(Ap + 4);
  float4 pb0 = *reinterpret_cast<const float4*>(Bp);
  float4 pb1 = *reinterpret_cast<const float4*>(Bp + 64);
  K1_STAGE(0);
  pa0 = *reinterpret_cast<const float4*>(Ap + 16);
  pa1 = *reinterpret_cast<const float4*>(Ap + 20);
  pb0 = *reinterpret_cast<const float4*>(Bp + (size_t)16 * DDIM);
  pb1 = *reinterpret_cast<const float4*>(Bp + (size_t)16 * DDIM + 64);

  for (int t = 0; t < 64; ++t) {
    __syncthreads();
    const int cur = t & 1;
    if (t < 63) {
      K1_STAGE(cur ^ 1);
      if (t < 62) {
        const size_t ko = (size_t)(t + 2) << 4;
        pa0 = *reinterpret_cast<const float4*>(Ap + ko);
        pa1 = *reinterpret_cast<const float4*>(Ap + ko + 4);
        pb0 = *reinterpret_cast<const float4*>(Bp + ko * DDIM);
        pb1 = *reinterpret_cast<const float4*>(Bp + ko * DDIM + 64);
      }
    }
    __builtin_amdgcn_s_setprio(1);
#pragma unroll
    for (int kp = 0; kp < 4; ++kp) {
      const int ka = (kp << 2) + lg;
      double a[4], b[4];
#pragma unroll
      for (int mi = 0; mi < 4; ++mi)
        a[mi] = (double)As[cur][ka][(wr << 6) + (mi << 4) + lr];
#pragma unroll
      for (int nj = 0; nj < 4; ++nj)
        b[nj] = (double)Bs[cur][ka][(wc << 6) + (nj << 4) + lr];
#pragma unroll
      for (int mi = 0; mi < 4; ++mi)
#pragma unroll
        for (int nj = 0; nj < 4; ++nj)
          acc[mi][nj] = __builtin_amdgcn_mfma_f64_16x16x4f64(
              a[mi], b[nj], acc[mi][nj], 0, 0, 0);
    }
    __builtin_amdgcn_s_setprio(0);
  }
#pragma unroll
  for (int mi = 0; mi < 4; ++mi)
#pragma unroll
    for (int nj = 0; nj < 4; ++nj)
#pragma unroll
      for (int rg = 0; rg < 4; ++rg) {
        int ri, ci;
        dmap(sel, lg, lr, rg, ri, ci);
        C[(size_t)(brow + (wr << 6) + (mi << 4) + ri) * DDIM +
          bcol + (wc << 6) + (nj << 4) + ci] = (float)acc[mi][nj][rg];
      }
}

// ---------------------------------------------------------------------------
// k1_repair: proven vector-f64 chain kernel; runs only if sel unknown. -- UNCHANGED
// ---------------------------------------------------------------------------
__global__ __launch_bounds__(256, 2)
void k1_repair(const float* __restrict__ A, const float* __restrict__ B,
               float* __restrict__ C, const int* __restrict__ selp) {
  if (selp[0] < 4) return;
  __shared__ double As[128][17];
  __shared__ double Bs[16][130];
  const int tid = threadIdx.x;
  const int lin = blockIdx.y * 8 + blockIdx.x;
  const int nlin = (lin & 7) * 64 + (lin >> 3);
  const int brow = (nlin >> 3) << 7;
  const int bcol = (nlin & 7) << 7;
  const int tx = tid & 15, ty = tid >> 4;
  const int ar = tid >> 1, aks = (tid & 1) << 3;
  const int bk = tid >> 4, btx = tid & 15;

  double acc[8][8];
#pragma unroll
  for (int i = 0; i < 8; ++i)
#pragma unroll
    for (int j = 0; j < 8; ++j) acc[i][j] = 0.0;

  const float* Aptr = &A[(size_t)(brow + ar) * DDIM + aks];
  const float* Bptr = &B[(size_t)bk * DDIM + bcol + (btx << 1)];

  float4 pa0, pa1;
  float2 pb[4];
  pa0 = *reinterpret_cast<const float4*>(Aptr);
  pa1 = *reinterpret_cast<const float4*>(Aptr + 4);
#pragma unroll
  for (int w = 0; w < 4; ++w)
    pb[w] = *reinterpret_cast<const float2*>(Bptr + (w << 5));

  for (int k0 = 0; k0 < DDIM; k0 += 16) {
    __syncthreads();
    As[ar][aks + 0] = (double)pa0.x; As[ar][aks + 1] = (double)pa0.y;
    As[ar][aks + 2] = (double)pa0.z; As[ar][aks + 3] = (double)pa0.w;
    As[ar][aks + 4] = (double)pa1.x; As[ar][aks + 5] = (double)pa1.y;
    As[ar][aks + 6] = (double)pa1.z; As[ar][aks + 7] = (double)pa1.w;
#pragma unroll
    for (int w = 0; w < 4; ++w) {
      Bs[bk][(btx << 1) + (w << 5) + 0] = (double)pb[w].x;
      Bs[bk][(btx << 1) + (w << 5) + 1] = (double)pb[w].y;
    }
    __syncthreads();
    if (k0 + 16 < DDIM) {
      pa0 = *reinterpret_cast<const float4*>(Aptr + k0 + 16);
      pa1 = *reinterpret_cast<const float4*>(Aptr + k0 + 20);
#pragma unroll
      for (int w = 0; w < 4; ++w)
        pb[w] = *reinterpret_cast<const float2*>(
            Bptr + (size_t)(k0 + 16) * DDIM + (w << 5));
    }
#pragma unroll 8
    for (int kk = 0; kk < 16; ++kk) {
      double a[8];
      double2 b[4];
#pragma unroll
      for (int i = 0; i < 8; ++i) a[i] = As[(ty << 3) + i][kk];
#pragma unroll
      for (int jj = 0; jj < 4; ++jj)
        b[jj] = *reinterpret_cast<const double2*>(&Bs[kk][(tx << 1) + (jj << 5)]);
#pragma unroll
      for (int i = 0; i < 8; ++i) {
#pragma unroll
        for (int jj = 0; jj < 4; ++jj) {
          acc[i][(jj << 1) + 0] = fma(a[i], b[jj].x, acc[i][(jj << 1) + 0]);
          acc[i][(jj << 1) + 1] = fma(a[i], b[jj].y, acc[i][(jj << 1) + 1]);
        }
      }
    }
  }
#pragma unroll
  for (int i = 0; i < 8; ++i) {
    float* crow = &C[(size_t)(brow + (ty << 3) + i) * DDIM + bcol + (tx << 1)];
#pragma unroll
    for (int jj = 0; jj < 4; ++jj) {
      float2 v = make_float2((float)acc[i][(jj << 1)],
                             (float)acc[i][(jj << 1) + 1]);
      *reinterpret_cast<float2*>(crow + (jj << 5)) = v;
    }
  }
}

// ---------------------------------------------------------------------------
// k2_mfma: approx scores, 256x256 tile, 512 threads, dbuf staging (R12),
// NOW with XCD-chunked block swizzle: XCD x gets 32 consecutive logical
// tiles = one (batch, 4-row-panel) slab; T panel (4 MB) stays in its L2.
// Pure block->tile remap: output bitwise identical.
// ---------------------------------------------------------------------------
#define K2_LOAD(koff)                                                         \
  do {                                                                        \
    _Pragma("unroll")                                                         \
    for (int q = 0; q < 4; ++q) {                                             \
      const int c = (q << 9) + tid;                                           \
      const int row = c >> 3;                                                 \
      const int gs = (c & 7) ^ (row & 7);                                     \
      const float* sT = &T[(size_t)(row0g + row) * DDIM + (koff) + (gs << 3)];\
      rT[2 * q] = *reinterpret_cast<const float4*>(sT);                       \
      rT[2 * q + 1] = *reinterpret_cast<const float4*>(sT + 4);               \
      const float* sH = &H[(size_t)(col0g + row) * DDIM + (koff) + (gs << 3)];\
      rH[2 * q] = *reinterpret_cast<const float4*>(sH);                       \
      rH[2 * q + 1] = *reinterpret_cast<const float4*>(sH + 4);               \
    }                                                                         \
  } while (0)

#define K2_STAGE(bi)                                                          \
  do {                                                                        \
    _Pragma("unroll")                                                         \
    for (int q = 0; q < 4; ++q) {                                             \
      const int c = (q << 9) + tid;                                           \
      uint4 o;                                                                \
      o.x = pkbf(rT[2 * q].x, rT[2 * q].y);                                   \
      o.y = pkbf(rT[2 * q].z, rT[2 * q].w);                                   \
      o.z = pkbf(rT[2 * q + 1].x, rT[2 * q + 1].y);                           \
      o.w = pkbf(rT[2 * q + 1].z, rT[2 * q + 1].w);                           \
      *reinterpret_cast<uint4*>(&u.stage[bi][0][c << 3]) = o;                 \
      uint4 o2;                                                               \
      o2.x = pkbf(rH[2 * q].x, rH[2 * q].y);                                  \
      o2.y = pkbf(rH[2 * q].z, rH[2 * q].w);                                  \
      o2.z = pkbf(rH[2 * q + 1].x, rH[2 * q + 1].y);                          \
      o2.w = pkbf(rH[2 * q + 1].z, rH[2 * q + 1].w);                          \
      *reinterpret_cast<uint4*>(&u.stage[bi][1][c << 3]) = o2;                \
    }                                                                         \
  } while (0)

__global__ __launch_bounds__(512, 1)
void k2_mfma(const float* __restrict__ T, const float* __restrict__ H,
             unsigned short* __restrict__ cand_v,
             unsigned char* __restrict__ cand_i) {
  __shared__ union {
    unsigned short stage[2][2][256 * 64];   // 128 KB (dbuf x {T,H})
    float Sl[64][264];                      // 67.6 KB
    struct {
      float mv[512][8];
      unsigned char mi[512][8];
    } mg;
  } u;
  const int tid = threadIdx.x;
  const int lane = tid & 63;
  const int w = tid >> 6;               // 0..7
  const int wr = w >> 2, wc = w & 3;    // 2 x 4 wave grid
  const int lr = lane & 15, lg = lane >> 4;
  // XCD-chunked bijective swizzle: 256 blocks, XCD (lin&7) gets 32
  // consecutive logical tiles (one batch-half: 4 row-panels x 8 col-blocks).
  const int lin = blockIdx.z * 64 + blockIdx.y * 8 + blockIdx.x;
  const int nl = (lin & 7) * 32 + (lin >> 3);
  const int bx = nl & 7;                // col block 0..7
  const int by = (nl >> 3) & 7;         // row block 0..7
  const int z = nl >> 6;                // batch 0..3
  const int brow = by << 8, bcol = bx << 8;
  const int row0g = z * SEQ + brow;
  const int col0g = z * SEQ + bcol;

  f32x4 acc[8][4];
#pragma unroll
  for (int mi = 0; mi < 8; ++mi)
#pragma unroll
    for (int nj = 0; nj < 4; ++nj)
      acc[mi][nj] = (f32x4){0.f, 0.f, 0.f, 0.f};

  float4 rT[8], rH[8];
  K2_LOAD(0);
  K2_STAGE(0);
  K2_LOAD(64);

  for (int t = 0; t < 16; ++t) {
    __syncthreads();
    const int cur = t & 1;
    if (t < 15) {
      K2_STAGE(cur ^ 1);
      if (t < 14) K2_LOAD((t + 2) << 6);
    }
#pragma unroll
    for (int kh2 = 0; kh2 < 2; ++kh2) {
      const int sl = (kh2 << 2) + lg;
      bf16x8 bfv[4];
#pragma unroll
      for (int nj = 0; nj < 4; ++nj) {
        const int rb = (wc << 6) + (nj << 4) + lr;
        bfv[nj] = *reinterpret_cast<const bf16x8*>(
            &u.stage[cur][1][(rb << 6) + ((sl ^ (rb & 7)) << 3)]);
      }
#pragma unroll
      for (int mi = 0; mi < 8; ++mi) {
        const int ra = (wr << 7) + (mi << 4) + lr;
        const bf16x8 af = *reinterpret_cast<const bf16x8*>(
            &u.stage[cur][0][(ra << 6) + ((sl ^ (ra & 7)) << 3)]);
#pragma unroll
        for (int nj = 0; nj < 4; ++nj)
          acc[mi][nj] = __builtin_amdgcn_mfma_f32_16x16x32_bf16(
              af, bfv[nj], acc[mi][nj], 0, 0, 0);
      }
    }
  }

  // epilogue: 4 phases of 64 rows (unchanged)
  const int srow = tid >> 3;     // 0..63
  const int qd = tid & 7;        // eighth (32 cols each)
#pragma unroll
  for (int p = 0; p < 4; ++p) {
    __syncthreads();
    if (wr == (p >> 1)) {
      const int mib = (p & 1) << 2;
#pragma unroll
      for (int mi2 = 0; mi2 < 4; ++mi2)
#pragma unroll
        for (int nj = 0; nj < 4; ++nj)
#pragma unroll
          for (int rg = 0; rg < 4; ++rg)
            u.Sl[(mi2 << 4) + (lg << 2) + rg][(wc << 6) + (nj << 4) + lr] =
                acc[mib + mi2][nj][rg];
    }
    __syncthreads();
    float v[KSEL];
    int ci[KSEL];
#pragma unroll
    for (int s = 0; s < KSEL; ++s) { v[s] = -3.0e38f; ci[s] = 0; }
    const int c0 = qd << 5;
    for (int c = 0; c < 32; ++c) {
      const float x = u.Sl[srow][c0 + c];
      if (x > v[KSEL - 1]) {
        float pv = x; int pc = c0 + c;
#pragma unroll
        for (int s = 0; s < KSEL; ++s) {
          if (x > v[s]) {
            const float tv = v[s]; const int tc = ci[s];
            v[s] = pv; ci[s] = pc; pv = tv; pc = tc;
          }
        }
      }
    }
    __syncthreads();   // all Sl reads done before mg overlay
#pragma unroll
    for (int s = 0; s < KSEL; ++s) {
      u.mg.mv[tid][s] = v[s];
      u.mg.mi[tid][s] = (unsigned char)ci[s];
    }
    __syncthreads();
    if (qd == 0) {
      float fv[KSEL];
      int fi[KSEL];
#pragma unroll
      for (int s = 0; s < KSEL; ++s) { fv[s] = -3.0e38f; fi[s] = 0; }
#pragma unroll
      for (int t2 = 0; t2 < 8; ++t2) {
#pragma unroll
        for (int s = 0; s < KSEL; ++s) {
          const float x = u.mg.mv[tid + t2][s];
          const int idx = u.mg.mi[tid + t2][s];
          if (x > fv[KSEL - 1]) {
            float pv = x; int pc = idx;
#pragma unroll
            for (int s2 = 0; s2 < KSEL; ++s2) {
              if (x > fv[s2]) {
                const float tv = fv[s2]; const int tc = fi[s2];
                fv[s2] = pv; fi[s2] = pc; pv = tv; pc = tc;
              }
            }
          }
        }
      }
      const size_t base =
          (size_t)(row0g + (p << 6) + srow) * 64 + ((size_t)bx << 3);
#pragma unroll
      for (int s = 0; s < KSEL; ++s) {
        cand_v[base + s] = f2bf(fv[s]);
        cand_i[base + s] = (unsigned char)fi[s];
      }
    }
  }
}

// ---------------------------------------------------------------------------
// kr_rescore -- UNCHANGED (R12: 2 rows/block, 2 waves/row, NCAND=12)
// ---------------------------------------------------------------------------
__global__ __launch_bounds__(256)
void kr_rescore(const float* __restrict__ T, const float* __restrict__ H,
                const unsigned short* __restrict__ cand_v,
                const unsigned char* __restrict__ cand_i,
                int* __restrict__ topi, float* __restrict__ topw,
                int* __restrict__ cnt) {
  __shared__ float smv[2][2][KSEL];
  __shared__ int smi[2][2][KSEL];
  const int tid = threadIdx.x, lane = tid & 63, w = tid >> 6;
  const int rl = w >> 1;
  const int half = w & 1;
  const int r = blockIdx.x * 2 + rl;
  const int b = r >> 11, iloc = r & (SEQ - 1);

  const size_t cbase = (size_t)r * 64;
  float v0 = bf2f(cand_v[cbase + lane]);
  int i0 = ((lane >> 3) << 8) + cand_i[cbase + lane];
  int keep = 0;
  for (int rnd = 0; rnd < NCAND; ++rnd) {
    float m = v0;
#pragma unroll
    for (int off = 32; off >= 1; off >>= 1) m = fmaxf(m, __shfl_xor(m, off));
    const unsigned long long bm = __ballot(v0 == m);
    const int owner = __ffsll(bm) - 1;
    const int oi = __shfl(i0, owner);
    if (lane == owner) v0 = -3.0e38f;
    if (lane == rnd) keep = oi;
  }

  const float* Trow = T + (size_t)r * DDIM;
  float4 t4[4];
#pragma unroll
  for (int q = 0; q < 4; ++q)
    t4[q] = *reinterpret_cast<const float4*>(&Trow[(q << 8) + (lane << 2)]);

  float t8v[KSEL];
  int t8i[KSEL];
#pragma unroll
  for (int p = 0; p < KSEL; ++p) { t8v[p] = -1.0f; t8i[p] = IMAXC; }

  const int c0 = half * (NCAND / 2);
  for (int c = c0; c < c0 + NCAND / 2; ++c) {
    const int j = __shfl(keep, c);
    const float* Hrow = H + ((size_t)(b << 11) + j) * DDIM;
    double s = 0.0;
#pragma unroll
    for (int q = 0; q < 4; ++q) {
      const float4 h = *reinterpret_cast<const float4*>(&Hrow[(q << 8) + (lane << 2)]);
      s = fma((double)t4[q].x, (double)h.x, s);
      s = fma((double)t4[q].y, (double)h.y, s);
      s = fma((double)t4[q].z, (double)h.z, s);
      s = fma((double)t4[q].w, (double)h.w, s);
    }
#pragma unroll
    for (int off = 1; off < 64; off <<= 1) s += __shfl_xor(s, off);
    const float aff = expf((float)s);
    const bool g7 = (aff > t8v[KSEL - 1]) ||
                    (aff == t8v[KSEL - 1] && j < t8i[KSEL - 1]);
    if (g7) {
      float pv = aff; int pi = j;
#pragma unroll
      for (int p = 0; p < KSEL; ++p) {
        const bool g = (aff > t8v[p]) || (aff == t8v[p] && j < t8i[p]);
        if (g) {
          const float tv = t8v[p]; const int ti = t8i[p];
          t8v[p] = pv; t8i[p] = pi; pv = tv; pi = ti;
        }
      }
    }
  }

  if (lane == 0) {
#pragma unroll
    for (int p = 0; p < KSEL; ++p) {
      smv[rl][half][p] = t8v[p];
      smi[rl][half][p] = t8i[p];
    }
  }
  __syncthreads();
  if (half == 0 && lane == 0) {
#pragma unroll
    for (int p = 0; p < KSEL; ++p) {
      const float x = smv[rl][1][p];
      const int jx = smi[rl][1][p];
      const bool g7 = (x > t8v[KSEL - 1]) ||
                      (x == t8v[KSEL - 1] && jx < t8i[KSEL - 1]);
      if (g7) {
        float pv = x; int pi = jx;
#pragma unroll
        for (int q = 0; q < KSEL; ++q) {
          const bool g = (x > t8v[q]) || (x == t8v[q] && jx < t8i[q]);
          if (g) {
            const float tv = t8v[q]; const int ti = t8i[q];
            t8v[q] = pv; t8i[q] = pi; pv = tv; pi = ti;
          }
        }
      }
    }
    float sum = 0.0f;
#pragma unroll
    for (int p = 0; p < KSEL; ++p) sum += t8v[p];
    sum += 1e-8f;
    int c8 = KSEL;
#pragma unroll
    for (int p = 0; p < KSEL; ++p)
      if (t8i[p] == iloc) --c8;
    cnt[r] = c8;
#pragma unroll
    for (int p = 0; p < KSEL; ++p) {
      topi[(size_t)r * KSEL + p] = t8i[p];
      topw[(size_t)r * KSEL + p] = t8v[p] / sum;
    }
  }
}

// ---------------------------------------------------------------------------
// k4_scan / k5_emit -- UNCHANGED
// ---------------------------------------------------------------------------
__global__ __launch_bounds__(1024)
void k4_scan(const int* __restrict__ cnt, int* __restrict__ off) {
  __shared__ int part[1024];
  const int t = threadIdx.x;
  int loc[8];
  int s = 0;
#pragma unroll
  for (int i = 0; i < 8; ++i) { loc[i] = s; s += cnt[t * 8 + i]; }
  part[t] = s;
  __syncthreads();
  for (int d = 1; d < 1024; d <<= 1) {
    const int add = (t >= d) ? part[t - d] : 0;
    __syncthreads();
    part[t] += add;
    __syncthreads();
  }
  const int base = (t == 0) ? 0 : part[t - 1];
#pragma unroll
  for (int i = 0; i < 8; ++i) off[t * 8 + i] = base + loc[i];
}

__global__ __launch_bounds__(256)
void k5_emit(const int* __restrict__ topi, const float* __restrict__ topw,
             const int* __restrict__ off, float* __restrict__ out, int E) {
  const int r = blockIdx.x * 256 + threadIdx.x;
  if (r >= NROWS) return;
  const int o = off[r];
  const int sloc = r & (SEQ - 1);
  const int bbase = r & ~(SEQ - 1);
  int e = 0;
#pragma unroll
  for (int p = 0; p < KSEL; ++p) {
    const int id = topi[(size_t)r * KSEL + p];
    const float w = topw[(size_t)r * KSEL + p];
    if (id != sloc) {
      const int pos = o + e;
      if (pos < E) {
        out[pos] = (float)r;
        out[(size_t)E + pos] = (float)(bbase + id);
        out[2 * (size_t)E + pos] = w;
      }
      ++e;
    }
  }
}

// ---------------------------------------------------------------------------
extern "C" void kernel_launch(void* const* d_in, const int* in_sizes, int n_in,
                              void* d_out, int out_size, void* d_ws,
                              size_t ws_size, hipStream_t stream) {
  const float* H = (const float*)d_in[0];      // [4,2048,1024]
  const float* Wphi = (const float*)d_in[1];   // [1024,1024]
  const float* Wpsi = (const float*)d_in[2];   // [1024,1024]
  float* out = (float*)d_out;
  const int E = out_size / 3;

  char* base = (char*)d_ws;
  float* T = (float*)base;                         // 32 MB
  char* regionX = base + 33554432;                 // 4 MB shared region
  float* Wc = (float*)regionX;                     //   Wc (dead after k1)
  unsigned short* cand_v = (unsigned short*)regionX;           // 1 MB used
  unsigned char* cand_i = (unsigned char*)(regionX + 2097152); // 0.5 MB used
  char* pp = regionX + 4194304;
  int* topi = (int*)pp;  pp += 262144;
  float* topw = (float*)pp; pp += 262144;
  int* cnt = (int*)pp;   pp += 32768;
  int* off = (int*)pp;   pp += 32768;
  int* sel = (int*)pp;

  // probe f64-MFMA D layout (writes sel in-stream before any consumer)
  kprobe<<<dim3(1), 64, 0, stream>>>(sel);
  // Wc = Wphi^T * Wpsi  (f64 MFMA, dbuf; vector repair if layout unknown)
  k0_mfma<<<dim3(16, 16), 256, 0, stream>>>(Wphi, Wpsi, Wc, sel);
  k0_repair<<<dim3(16, 16), 256, 0, stream>>>(Wphi, Wpsi, Wc, sel);
  // T = H * Wc  (f64 MFMA, dbuf + setprio; vector repair if layout unknown)
  k1_mfma<<<dim3(8, 64), 256, 0, stream>>>(H, Wc, T, sel);
  k1_repair<<<dim3(8, 64), 256, 0, stream>>>(H, Wc, T, sel);
  // approx MFMA scores, 256^2 tile, dbuf staging, XCD-chunked swizzle
  k2_mfma<<<dim3(8, 8, 4), 512, 0, stream>>>(T, H, cand_v, cand_i);
  // extraction + exact f64 rescore (2 waves/row) + stable top-8 + counts
  kr_rescore<<<dim3(NROWS / 2), 256, 0, stream>>>(T, H, cand_v, cand_i,
                                                  topi, topw, cnt);
  // prefix scan + emit
  k4_scan<<<dim3(1), 1024, 0, stream>>>(cnt, off);
  k5_emit<<<dim3(NROWS / 256), 256, 0, stream>>>(topi, topw, off, out, E);
}

// Round 15
// 549.697 us; speedup vs baseline: 1.0534x; 1.0062x over previous
//
#include <hip/hip_runtime.h>
#include <cmath>

#define SEQ 2048
#define DDIM 1024
#define NROWS 8192   // B*S
#define KSEL 8
#define NCAND 12
#define IMAXC 0x7fffffff

typedef __attribute__((ext_vector_type(8))) short bf16x8;
typedef __attribute__((ext_vector_type(4))) float f32x4;
typedef __attribute__((ext_vector_type(4))) double f64x4;

__device__ __forceinline__ unsigned short f2bf(float f) {
  unsigned u = __builtin_bit_cast(unsigned, f);
  u = (u + 0x7fffu + ((u >> 16) & 1u)) >> 16;
  return (unsigned short)u;
}
__device__ __forceinline__ float bf2f(unsigned short h) {
  unsigned u = ((unsigned)h) << 16;
  return __builtin_bit_cast(float, u);
}
__device__ __forceinline__ unsigned pkbf(float a, float b) {
  unsigned r;
  asm("v_cvt_pk_bf16_f32 %0, %1, %2" : "=v"(r) : "v"(a), "v"(b));
  return r;
}
// D-fragment (row,col) within a 16x16 tile for f64 mfma, by probed layout sel
__device__ __forceinline__ void dmap(int sel, int lg, int lr, int rg,
                                     int& ri, int& ci) {
  switch (sel) {
    case 0:  ri = (lg << 2) + rg; ci = lr; break;
    case 1:  ri = lg + (rg << 2); ci = lr; break;
    case 2:  ri = lr; ci = (lg << 2) + rg; break;
    default: ri = lr; ci = lg + (rg << 2); break;
  }
}

// ---------------------------------------------------------------------------
// kprobe: one wave determines the f64-MFMA D layout (exact integer check).
// sel=4 -> unknown -> vector repair kernels take over. -- UNCHANGED
// ---------------------------------------------------------------------------
__global__ void kprobe(int* __restrict__ sel) {
  const int lane = threadIdx.x;
  const int lr = lane & 15, lg = lane >> 4;
  const double a = (double)(4 * lr + lg + 1);
  const double b = (double)(9 * lr + 5 * lg + 2);
  f64x4 d = (f64x4){0.0, 0.0, 0.0, 0.0};
  d = __builtin_amdgcn_mfma_f64_16x16x4f64(a, b, d, 0, 0, 0);
  int my = 4;
  for (int s = 3; s >= 0; --s) {
    bool ok = true;
    for (int rg = 0; rg < 4; ++rg) {
      int ri, ci;
      dmap(s, lg, lr, rg, ri, ci);
      double e = 0.0;
      for (int k = 0; k < 4; ++k)
        e += (double)(4 * ri + k + 1) * (double)(9 * ci + 5 * k + 2);
      ok = ok && (d[rg] == e);
    }
    if (__all(ok)) my = s;
  }
  if (lane == 0) sel[0] = my;
}

// ---------------------------------------------------------------------------
// k0_mfma: Wc = Wphi^T * Wpsi (TN, f64 MFMA), dbuf, 1 barrier/step. -- UNCHANGED
// ---------------------------------------------------------------------------
#define K0_STAGE(bi)                                        \
  do {                                                      \
    *reinterpret_cast<float4*>(&As[bi][kr][c4]) = pa0;      \
    *reinterpret_cast<float4*>(&As[bi][kr][c4 + 32]) = pa1; \
    *reinterpret_cast<float4*>(&Bs[bi][kr][c4]) = pb0;      \
    *reinterpret_cast<float4*>(&Bs[bi][kr][c4 + 32]) = pb1; \
  } while (0)

__global__ __launch_bounds__(256, 2)
void k0_mfma(const float* __restrict__ A, const float* __restrict__ B,
             float* __restrict__ C, const int* __restrict__ selp) {
  const int sel = selp[0];
  if (sel >= 4) return;
  __shared__ float As[2][32][72];
  __shared__ float Bs[2][32][72];
  const int tid = threadIdx.x;
  const int lane = tid & 63, w = tid >> 6;
  const int wr = w >> 1, wc = w & 1;
  const int lr = lane & 15, lg = lane >> 4;
  const int brow = blockIdx.y << 6, bcol = blockIdx.x << 6;
  const int kr = tid >> 3, c4 = (tid & 7) << 2;

  f64x4 acc[2][2];
#pragma unroll
  for (int mi = 0; mi < 2; ++mi)
#pragma unroll
    for (int nj = 0; nj < 2; ++nj)
      acc[mi][nj] = (f64x4){0.0, 0.0, 0.0, 0.0};

  const float* Ap = &A[(size_t)kr * DDIM + brow + c4];
  const float* Bp = &B[(size_t)kr * DDIM + bcol + c4];
  float4 pa0 = *reinterpret_cast<const float4*>(Ap);
  float4 pa1 = *reinterpret_cast<const float4*>(Ap + 32);
  float4 pb0 = *reinterpret_cast<const float4*>(Bp);
  float4 pb1 = *reinterpret_cast<const float4*>(Bp + 32);
  K0_STAGE(0);
  {
    const size_t nk = (size_t)32 * DDIM;
    pa0 = *reinterpret_cast<const float4*>(Ap + nk);
    pa1 = *reinterpret_cast<const float4*>(Ap + nk + 32);
    pb0 = *reinterpret_cast<const float4*>(Bp + nk);
    pb1 = *reinterpret_cast<const float4*>(Bp + nk + 32);
  }

  for (int t = 0; t < 32; ++t) {
    __syncthreads();
    const int cur = t & 1;
    if (t < 31) {
      K0_STAGE(cur ^ 1);
      if (t < 30) {
        const size_t nk = (size_t)(t + 2) * 32 * DDIM;
        pa0 = *reinterpret_cast<const float4*>(Ap + nk);
        pa1 = *reinterpret_cast<const float4*>(Ap + nk + 32);
        pb0 = *reinterpret_cast<const float4*>(Bp + nk);
        pb1 = *reinterpret_cast<const float4*>(Bp + nk + 32);
      }
    }
    __builtin_amdgcn_s_setprio(1);
#pragma unroll
    for (int kp = 0; kp < 8; ++kp) {
      const int ka = (kp << 2) + lg;
      double a[2], b[2];
#pragma unroll
      for (int mi = 0; mi < 2; ++mi)
        a[mi] = (double)As[cur][ka][(wr << 5) + (mi << 4) + lr];
#pragma unroll
      for (int nj = 0; nj < 2; ++nj)
        b[nj] = (double)Bs[cur][ka][(wc << 5) + (nj << 4) + lr];
#pragma unroll
      for (int mi = 0; mi < 2; ++mi)
#pragma unroll
        for (int nj = 0; nj < 2; ++nj)
          acc[mi][nj] = __builtin_amdgcn_mfma_f64_16x16x4f64(
              a[mi], b[nj], acc[mi][nj], 0, 0, 0);
    }
    __builtin_amdgcn_s_setprio(0);
  }
#pragma unroll
  for (int mi = 0; mi < 2; ++mi)
#pragma unroll
    for (int nj = 0; nj < 2; ++nj)
#pragma unroll
      for (int rg = 0; rg < 4; ++rg) {
        int ri, ci;
        dmap(sel, lg, lr, rg, ri, ci);
        C[(size_t)(brow + (wr << 5) + (mi << 4) + ri) * DDIM +
          bcol + (wc << 5) + (nj << 4) + ci] = (float)acc[mi][nj][rg];
      }
}

// ---------------------------------------------------------------------------
// k0_repair: proven vector-f64 TN kernel; runs only if sel unknown. -- UNCHANGED
// ---------------------------------------------------------------------------
__global__ __launch_bounds__(256)
void k0_repair(const float* __restrict__ A, const float* __restrict__ B,
               float* __restrict__ C, const int* __restrict__ selp) {
  if (selp[0] < 4) return;
  __shared__ __align__(16) float As[32][68];
  __shared__ __align__(16) float Bs[32][68];
  const int tid = threadIdx.x;
  const int tx = tid & 15, ty = tid >> 4;
  const int brow = blockIdx.y << 6;
  const int bcol = blockIdx.x << 6;
  double acc[4][4] = {};
  for (int k0 = 0; k0 < DDIM; k0 += 32) {
#pragma unroll
    for (int i = 0; i < 2; ++i) {
      const int f = tid + (i << 8);
      const int r = f >> 4;
      const int c4 = (f & 15) << 2;
      *reinterpret_cast<float4*>(&As[r][c4]) =
          *reinterpret_cast<const float4*>(&A[(size_t)(k0 + r) * DDIM + brow + c4]);
      *reinterpret_cast<float4*>(&Bs[r][c4]) =
          *reinterpret_cast<const float4*>(&B[(size_t)(k0 + r) * DDIM + bcol + c4]);
    }
    __syncthreads();
#pragma unroll
    for (int kk = 0; kk < 32; ++kk) {
      const float4 a = *reinterpret_cast<const float4*>(&As[kk][ty << 2]);
      const float4 b = *reinterpret_cast<const float4*>(&Bs[kk][tx << 2]);
      const double ad[4] = {a.x, a.y, a.z, a.w};
      const double bd[4] = {b.x, b.y, b.z, b.w};
#pragma unroll
      for (int i = 0; i < 4; ++i)
#pragma unroll
        for (int j = 0; j < 4; ++j)
          acc[i][j] = fma(ad[i], bd[j], acc[i][j]);
    }
    __syncthreads();
  }
#pragma unroll
  for (int i = 0; i < 4; ++i) {
    float4 v = make_float4((float)acc[i][0], (float)acc[i][1],
                           (float)acc[i][2], (float)acc[i][3]);
    *reinterpret_cast<float4*>(
        &C[(size_t)(brow + (ty << 2) + i) * DDIM + bcol + (tx << 2)]) = v;
  }
}

// ---------------------------------------------------------------------------
// k1_mfma: T = H * Wc (NN, f64 MFMA). NOW BK=32: half the barriers (32 vs
// 64), 32 MFMA per step, dbuf LDS 73.7 KB (still 2 blocks/CU). Per-element
// mfma chain is the SAME k-ascending sequence as BK=16 => T bitwise
// identical. Staging maps preserve the proven conflict patterns.
// ---------------------------------------------------------------------------
#define K1_STAGE(bi)                                                \
  do {                                                              \
    As[bi][akh + 0][ar] = pa0.x;  As[bi][akh + 1][ar] = pa0.y;      \
    As[bi][akh + 2][ar] = pa0.z;  As[bi][akh + 3][ar] = pa0.w;      \
    As[bi][akh + 4][ar] = pa1.x;  As[bi][akh + 5][ar] = pa1.y;      \
    As[bi][akh + 6][ar] = pa1.z;  As[bi][akh + 7][ar] = pa1.w;      \
    As[bi][akh + 16][ar] = pa2.x; As[bi][akh + 17][ar] = pa2.y;     \
    As[bi][akh + 18][ar] = pa2.z; As[bi][akh + 19][ar] = pa2.w;     \
    As[bi][akh + 20][ar] = pa3.x; As[bi][akh + 21][ar] = pa3.y;     \
    As[bi][akh + 22][ar] = pa3.z; As[bi][akh + 23][ar] = pa3.w;     \
    *reinterpret_cast<float4*>(&Bs[bi][bk][bc4]) = pb0;             \
    *reinterpret_cast<float4*>(&Bs[bi][bk][bc4 + 64]) = pb1;        \
    *reinterpret_cast<float4*>(&Bs[bi][bk + 16][bc4]) = pb2;        \
    *reinterpret_cast<float4*>(&Bs[bi][bk + 16][bc4 + 64]) = pb3;   \
  } while (0)

#define K1_LOAD(koff)                                                        \
  do {                                                                       \
    pa0 = *reinterpret_cast<const float4*>(Ap + (koff));                     \
    pa1 = *reinterpret_cast<const float4*>(Ap + (koff) + 4);                 \
    pa2 = *reinterpret_cast<const float4*>(Ap + (koff) + 16);                \
    pa3 = *reinterpret_cast<const float4*>(Ap + (koff) + 20);                \
    pb0 = *reinterpret_cast<const float4*>(Bp + (size_t)(koff) * DDIM);      \
    pb1 = *reinterpret_cast<const float4*>(Bp + (size_t)(koff) * DDIM + 64); \
    pb2 = *reinterpret_cast<const float4*>(Bp + (size_t)((koff) + 16) * DDIM);      \
    pb3 = *reinterpret_cast<const float4*>(Bp + (size_t)((koff) + 16) * DDIM + 64); \
  } while (0)

__global__ __launch_bounds__(256, 2)
void k1_mfma(const float* __restrict__ A, const float* __restrict__ B,
             float* __restrict__ C, const int* __restrict__ selp) {
  const int sel = selp[0];
  if (sel >= 4) return;
  __shared__ float As[2][32][144];
  __shared__ float Bs[2][32][144];
  const int tid = threadIdx.x;
  const int lin = blockIdx.y * 8 + blockIdx.x;          // 512 blocks
  const int nlin = (lin & 7) * 64 + (lin >> 3);         // bijective XCD swizzle
  const int brow = (nlin >> 3) << 7;
  const int bcol = (nlin & 7) << 7;
  const int lane = tid & 63, w = tid >> 6;
  const int wr = w >> 1, wc = w & 1;
  const int lr = lane & 15, lg = lane >> 4;
  const int ar = tid >> 1, akh = (tid & 1) << 3;   // A: row, k-half (0/8)
  const int bk = tid >> 4, bc4 = (tid & 15) << 2;  // B: k-row (0..15), col

  f64x4 acc[4][4];
#pragma unroll
  for (int mi = 0; mi < 4; ++mi)
#pragma unroll
    for (int nj = 0; nj < 4; ++nj)
      acc[mi][nj] = (f64x4){0.0, 0.0, 0.0, 0.0};

  const float* Ap = &A[(size_t)(brow + ar) * DDIM + akh];
  const float* Bp = &B[(size_t)bk * DDIM + bcol + bc4];

  float4 pa0, pa1, pa2, pa3, pb0, pb1, pb2, pb3;
  K1_LOAD(0);
  K1_STAGE(0);
  K1_LOAD(32);

  for (int t = 0; t < 32; ++t) {
    __syncthreads();
    const int cur = t & 1;
    if (t < 31) {
      K1_STAGE(cur ^ 1);
      if (t < 30) K1_LOAD((size_t)(t + 2) << 5);
    }
    __builtin_amdgcn_s_setprio(1);
#pragma unroll
    for (int kp = 0; kp < 8; ++kp) {
      const int ka = (kp << 2) + lg;
      double a[4], b[4];
#pragma unroll
      for (int mi = 0; mi < 4; ++mi)
        a[mi] = (double)As[cur][ka][(wr << 6) + (mi << 4) + lr];
#pragma unroll
      for (int nj = 0; nj < 4; ++nj)
        b[nj] = (double)Bs[cur][ka][(wc << 6) + (nj << 4) + lr];
#pragma unroll
      for (int mi = 0; mi < 4; ++mi)
#pragma unroll
        for (int nj = 0; nj < 4; ++nj)
          acc[mi][nj] = __builtin_amdgcn_mfma_f64_16x16x4f64(
              a[mi], b[nj], acc[mi][nj], 0, 0, 0);
    }
    __builtin_amdgcn_s_setprio(0);
  }
#pragma unroll
  for (int mi = 0; mi < 4; ++mi)
#pragma unroll
    for (int nj = 0; nj < 4; ++nj)
#pragma unroll
      for (int rg = 0; rg < 4; ++rg) {
        int ri, ci;
        dmap(sel, lg, lr, rg, ri, ci);
        C[(size_t)(brow + (wr << 6) + (mi << 4) + ri) * DDIM +
          bcol + (wc << 6) + (nj << 4) + ci] = (float)acc[mi][nj][rg];
      }
}

// ---------------------------------------------------------------------------
// k1_repair: proven vector-f64 chain kernel; runs only if sel unknown. -- UNCHANGED
// ---------------------------------------------------------------------------
__global__ __launch_bounds__(256, 2)
void k1_repair(const float* __restrict__ A, const float* __restrict__ B,
               float* __restrict__ C, const int* __restrict__ selp) {
  if (selp[0] < 4) return;
  __shared__ double As[128][17];
  __shared__ double Bs[16][130];
  const int tid = threadIdx.x;
  const int lin = blockIdx.y * 8 + blockIdx.x;
  const int nlin = (lin & 7) * 64 + (lin >> 3);
  const int brow = (nlin >> 3) << 7;
  const int bcol = (nlin & 7) << 7;
  const int tx = tid & 15, ty = tid >> 4;
  const int ar = tid >> 1, aks = (tid & 1) << 3;
  const int bk = tid >> 4, btx = tid & 15;

  double acc[8][8];
#pragma unroll
  for (int i = 0; i < 8; ++i)
#pragma unroll
    for (int j = 0; j < 8; ++j) acc[i][j] = 0.0;

  const float* Aptr = &A[(size_t)(brow + ar) * DDIM + aks];
  const float* Bptr = &B[(size_t)bk * DDIM + bcol + (btx << 1)];

  float4 pa0, pa1;
  float2 pb[4];
  pa0 = *reinterpret_cast<const float4*>(Aptr);
  pa1 = *reinterpret_cast<const float4*>(Aptr + 4);
#pragma unroll
  for (int w = 0; w < 4; ++w)
    pb[w] = *reinterpret_cast<const float2*>(Bptr + (w << 5));

  for (int k0 = 0; k0 < DDIM; k0 += 16) {
    __syncthreads();
    As[ar][aks + 0] = (double)pa0.x; As[ar][aks + 1] = (double)pa0.y;
    As[ar][aks + 2] = (double)pa0.z; As[ar][aks + 3] = (double)pa0.w;
    As[ar][aks + 4] = (double)pa1.x; As[ar][aks + 5] = (double)pa1.y;
    As[ar][aks + 6] = (double)pa1.z; As[ar][aks + 7] = (double)pa1.w;
#pragma unroll
    for (int w = 0; w < 4; ++w) {
      Bs[bk][(btx << 1) + (w << 5) + 0] = (double)pb[w].x;
      Bs[bk][(btx << 1) + (w << 5) + 1] = (double)pb[w].y;
    }
    __syncthreads();
    if (k0 + 16 < DDIM) {
      pa0 = *reinterpret_cast<const float4*>(Aptr + k0 + 16);
      pa1 = *reinterpret_cast<const float4*>(Aptr + k0 + 20);
#pragma unroll
      for (int w = 0; w < 4; ++w)
        pb[w] = *reinterpret_cast<const float2*>(
            Bptr + (size_t)(k0 + 16) * DDIM + (w << 5));
    }
#pragma unroll 8
    for (int kk = 0; kk < 16; ++kk) {
      double a[8];
      double2 b[4];
#pragma unroll
      for (int i = 0; i < 8; ++i) a[i] = As[(ty << 3) + i][kk];
#pragma unroll
      for (int jj = 0; jj < 4; ++jj)
        b[jj] = *reinterpret_cast<const double2*>(&Bs[kk][(tx << 1) + (jj << 5)]);
#pragma unroll
      for (int i = 0; i < 8; ++i) {
#pragma unroll
        for (int jj = 0; jj < 4; ++jj) {
          acc[i][(jj << 1) + 0] = fma(a[i], b[jj].x, acc[i][(jj << 1) + 0]);
          acc[i][(jj << 1) + 1] = fma(a[i], b[jj].y, acc[i][(jj << 1) + 1]);
        }
      }
    }
  }
#pragma unroll
  for (int i = 0; i < 8; ++i) {
    float* crow = &C[(size_t)(brow + (ty << 3) + i) * DDIM + bcol + (tx << 1)];
#pragma unroll
    for (int jj = 0; jj < 4; ++jj) {
      float2 v = make_float2((float)acc[i][(jj << 1)],
                             (float)acc[i][(jj << 1) + 1]);
      *reinterpret_cast<float2*>(crow + (jj << 5)) = v;
    }
  }
}

// ---------------------------------------------------------------------------
// k2_mfma: approx scores, 256x256 tile, 512 threads, dbuf staging,
// XCD-chunked swizzle. -- UNCHANGED (R14)
// ---------------------------------------------------------------------------
#define K2_LOAD(koff)                                                         \
  do {                                                                        \
    _Pragma("unroll")                                                         \
    for (int q = 0; q < 4; ++q) {                                             \
      const int c = (q << 9) + tid;                                           \
      const int row = c >> 3;                                                 \
      const int gs = (c & 7) ^ (row & 7);                                     \
      const float* sT = &T[(size_t)(row0g + row) * DDIM + (koff) + (gs << 3)];\
      rT[2 * q] = *reinterpret_cast<const float4*>(sT);                       \
      rT[2 * q + 1] = *reinterpret_cast<const float4*>(sT + 4);               \
      const float* sH = &H[(size_t)(col0g + row) * DDIM + (koff) + (gs << 3)];\
      rH[2 * q] = *reinterpret_cast<const float4*>(sH);                       \
      rH[2 * q + 1] = *reinterpret_cast<const float4*>(sH + 4);               \
    }                                                                         \
  } while (0)

#define K2_STAGE(bi)                                                          \
  do {                                                                        \
    _Pragma("unroll")                                                         \
    for (int q = 0; q < 4; ++q) {                                             \
      const int c = (q << 9) + tid;                                           \
      uint4 o;                                                                \
      o.x = pkbf(rT[2 * q].x, rT[2 * q].y);                                   \
      o.y = pkbf(rT[2 * q].z, rT[2 * q].w);                                   \
      o.z = pkbf(rT[2 * q + 1].x, rT[2 * q + 1].y);                           \
      o.w = pkbf(rT[2 * q + 1].z, rT[2 * q + 1].w);                           \
      *reinterpret_cast<uint4*>(&u.stage[bi][0][c << 3]) = o;                 \
      uint4 o2;                                                               \
      o2.x = pkbf(rH[2 * q].x, rH[2 * q].y);                                  \
      o2.y = pkbf(rH[2 * q].z, rH[2 * q].w);                                  \
      o2.z = pkbf(rH[2 * q + 1].x, rH[2 * q + 1].y);                          \
      o2.w = pkbf(rH[2 * q + 1].z, rH[2 * q + 1].w);                          \
      *reinterpret_cast<uint4*>(&u.stage[bi][1][c << 3]) = o2;                \
    }                                                                         \
  } while (0)

__global__ __launch_bounds__(512, 1)
void k2_mfma(const float* __restrict__ T, const float* __restrict__ H,
             unsigned short* __restrict__ cand_v,
             unsigned char* __restrict__ cand_i) {
  __shared__ union {
    unsigned short stage[2][2][256 * 64];   // 128 KB (dbuf x {T,H})
    float Sl[64][264];                      // 67.6 KB
    struct {
      float mv[512][8];
      unsigned char mi[512][8];
    } mg;
  } u;
  const int tid = threadIdx.x;
  const int lane = tid & 63;
  const int w = tid >> 6;               // 0..7
  const int wr = w >> 2, wc = w & 3;    // 2 x 4 wave grid
  const int lr = lane & 15, lg = lane >> 4;
  const int lin = blockIdx.z * 64 + blockIdx.y * 8 + blockIdx.x;
  const int nl = (lin & 7) * 32 + (lin >> 3);
  const int bx = nl & 7;                // col block 0..7
  const int by = (nl >> 3) & 7;         // row block 0..7
  const int z = nl >> 6;                // batch 0..3
  const int brow = by << 8, bcol = bx << 8;
  const int row0g = z * SEQ + brow;
  const int col0g = z * SEQ + bcol;

  f32x4 acc[8][4];
#pragma unroll
  for (int mi = 0; mi < 8; ++mi)
#pragma unroll
    for (int nj = 0; nj < 4; ++nj)
      acc[mi][nj] = (f32x4){0.f, 0.f, 0.f, 0.f};

  float4 rT[8], rH[8];
  K2_LOAD(0);
  K2_STAGE(0);
  K2_LOAD(64);

  for (int t = 0; t < 16; ++t) {
    __syncthreads();
    const int cur = t & 1;
    if (t < 15) {
      K2_STAGE(cur ^ 1);
      if (t < 14) K2_LOAD((t + 2) << 6);
    }
#pragma unroll
    for (int kh2 = 0; kh2 < 2; ++kh2) {
      const int sl = (kh2 << 2) + lg;
      bf16x8 bfv[4];
#pragma unroll
      for (int nj = 0; nj < 4; ++nj) {
        const int rb = (wc << 6) + (nj << 4) + lr;
        bfv[nj] = *reinterpret_cast<const bf16x8*>(
            &u.stage[cur][1][(rb << 6) + ((sl ^ (rb & 7)) << 3)]);
      }
#pragma unroll
      for (int mi = 0; mi < 8; ++mi) {
        const int ra = (wr << 7) + (mi << 4) + lr;
        const bf16x8 af = *reinterpret_cast<const bf16x8*>(
            &u.stage[cur][0][(ra << 6) + ((sl ^ (ra & 7)) << 3)]);
#pragma unroll
        for (int nj = 0; nj < 4; ++nj)
          acc[mi][nj] = __builtin_amdgcn_mfma_f32_16x16x32_bf16(
              af, bfv[nj], acc[mi][nj], 0, 0, 0);
      }
    }
  }

  // epilogue: 4 phases of 64 rows (unchanged)
  const int srow = tid >> 3;     // 0..63
  const int qd = tid & 7;        // eighth (32 cols each)
#pragma unroll
  for (int p = 0; p < 4; ++p) {
    __syncthreads();
    if (wr == (p >> 1)) {
      const int mib = (p & 1) << 2;
#pragma unroll
      for (int mi2 = 0; mi2 < 4; ++mi2)
#pragma unroll
        for (int nj = 0; nj < 4; ++nj)
#pragma unroll
          for (int rg = 0; rg < 4; ++rg)
            u.Sl[(mi2 << 4) + (lg << 2) + rg][(wc << 6) + (nj << 4) + lr] =
                acc[mib + mi2][nj][rg];
    }
    __syncthreads();
    float v[KSEL];
    int ci[KSEL];
#pragma unroll
    for (int s = 0; s < KSEL; ++s) { v[s] = -3.0e38f; ci[s] = 0; }
    const int c0 = qd << 5;
    for (int c = 0; c < 32; ++c) {
      const float x = u.Sl[srow][c0 + c];
      if (x > v[KSEL - 1]) {
        float pv = x; int pc = c0 + c;
#pragma unroll
        for (int s = 0; s < KSEL; ++s) {
          if (x > v[s]) {
            const float tv = v[s]; const int tc = ci[s];
            v[s] = pv; ci[s] = pc; pv = tv; pc = tc;
          }
        }
      }
    }
    __syncthreads();   // all Sl reads done before mg overlay
#pragma unroll
    for (int s = 0; s < KSEL; ++s) {
      u.mg.mv[tid][s] = v[s];
      u.mg.mi[tid][s] = (unsigned char)ci[s];
    }
    __syncthreads();
    if (qd == 0) {
      float fv[KSEL];
      int fi[KSEL];
#pragma unroll
      for (int s = 0; s < KSEL; ++s) { fv[s] = -3.0e38f; fi[s] = 0; }
#pragma unroll
      for (int t2 = 0; t2 < 8; ++t2) {
#pragma unroll
        for (int s = 0; s < KSEL; ++s) {
          const float x = u.mg.mv[tid + t2][s];
          const int idx = u.mg.mi[tid + t2][s];
          if (x > fv[KSEL - 1]) {
            float pv = x; int pc = idx;
#pragma unroll
            for (int s2 = 0; s2 < KSEL; ++s2) {
              if (x > fv[s2]) {
                const float tv = fv[s2]; const int tc = fi[s2];
                fv[s2] = pv; fi[s2] = pc; pv = tv; pc = tc;
              }
            }
          }
        }
      }
      const size_t base =
          (size_t)(row0g + (p << 6) + srow) * 64 + ((size_t)bx << 3);
#pragma unroll
      for (int s = 0; s < KSEL; ++s) {
        cand_v[base + s] = f2bf(fv[s]);
        cand_i[base + s] = (unsigned char)fi[s];
      }
    }
  }
}

// ---------------------------------------------------------------------------
// kr_rescore -- UNCHANGED (R12: 2 rows/block, 2 waves/row, NCAND=12)
// ---------------------------------------------------------------------------
__global__ __launch_bounds__(256)
void kr_rescore(const float* __restrict__ T, const float* __restrict__ H,
                const unsigned short* __restrict__ cand_v,
                const unsigned char* __restrict__ cand_i,
                int* __restrict__ topi, float* __restrict__ topw,
                int* __restrict__ cnt) {
  __shared__ float smv[2][2][KSEL];
  __shared__ int smi[2][2][KSEL];
  const int tid = threadIdx.x, lane = tid & 63, w = tid >> 6;
  const int rl = w >> 1;
  const int half = w & 1;
  const int r = blockIdx.x * 2 + rl;
  const int b = r >> 11, iloc = r & (SEQ - 1);

  const size_t cbase = (size_t)r * 64;
  float v0 = bf2f(cand_v[cbase + lane]);
  int i0 = ((lane >> 3) << 8) + cand_i[cbase + lane];
  int keep = 0;
  for (int rnd = 0; rnd < NCAND; ++rnd) {
    float m = v0;
#pragma unroll
    for (int off = 32; off >= 1; off >>= 1) m = fmaxf(m, __shfl_xor(m, off));
    const unsigned long long bm = __ballot(v0 == m);
    const int owner = __ffsll(bm) - 1;
    const int oi = __shfl(i0, owner);
    if (lane == owner) v0 = -3.0e38f;
    if (lane == rnd) keep = oi;
  }

  const float* Trow = T + (size_t)r * DDIM;
  float4 t4[4];
#pragma unroll
  for (int q = 0; q < 4; ++q)
    t4[q] = *reinterpret_cast<const float4*>(&Trow[(q << 8) + (lane << 2)]);

  float t8v[KSEL];
  int t8i[KSEL];
#pragma unroll
  for (int p = 0; p < KSEL; ++p) { t8v[p] = -1.0f; t8i[p] = IMAXC; }

  const int c0 = half * (NCAND / 2);
  for (int c = c0; c < c0 + NCAND / 2; ++c) {
    const int j = __shfl(keep, c);
    const float* Hrow = H + ((size_t)(b << 11) + j) * DDIM;
    double s = 0.0;
#pragma unroll
    for (int q = 0; q < 4; ++q) {
      const float4 h = *reinterpret_cast<const float4*>(&Hrow[(q << 8) + (lane << 2)]);
      s = fma((double)t4[q].x, (double)h.x, s);
      s = fma((double)t4[q].y, (double)h.y, s);
      s = fma((double)t4[q].z, (double)h.z, s);
      s = fma((double)t4[q].w, (double)h.w, s);
    }
#pragma unroll
    for (int off = 1; off < 64; off <<= 1) s += __shfl_xor(s, off);
    const float aff = expf((float)s);
    const bool g7 = (aff > t8v[KSEL - 1]) ||
                    (aff == t8v[KSEL - 1] && j < t8i[KSEL - 1]);
    if (g7) {
      float pv = aff; int pi = j;
#pragma unroll
      for (int p = 0; p < KSEL; ++p) {
        const bool g = (aff > t8v[p]) || (aff == t8v[p] && j < t8i[p]);
        if (g) {
          const float tv = t8v[p]; const int ti = t8i[p];
          t8v[p] = pv; t8i[p] = pi; pv = tv; pi = ti;
        }
      }
    }
  }

  if (lane == 0) {
#pragma unroll
    for (int p = 0; p < KSEL; ++p) {
      smv[rl][half][p] = t8v[p];
      smi[rl][half][p] = t8i[p];
    }
  }
  __syncthreads();
  if (half == 0 && lane == 0) {
#pragma unroll
    for (int p = 0; p < KSEL; ++p) {
      const float x = smv[rl][1][p];
      const int jx = smi[rl][1][p];
      const bool g7 = (x > t8v[KSEL - 1]) ||
                      (x == t8v[KSEL - 1] && jx < t8i[KSEL - 1]);
      if (g7) {
        float pv = x; int pi = jx;
#pragma unroll
        for (int q = 0; q < KSEL; ++q) {
          const bool g = (x > t8v[q]) || (x == t8v[q] && jx < t8i[q]);
          if (g) {
            const float tv = t8v[q]; const int ti = t8i[q];
            t8v[q] = pv; t8i[q] = pi; pv = tv; pi = ti;
          }
        }
      }
    }
    float sum = 0.0f;
#pragma unroll
    for (int p = 0; p < KSEL; ++p) sum += t8v[p];
    sum += 1e-8f;
    int c8 = KSEL;
#pragma unroll
    for (int p = 0; p < KSEL; ++p)
      if (t8i[p] == iloc) --c8;
    cnt[r] = c8;
#pragma unroll
    for (int p = 0; p < KSEL; ++p) {
      topi[(size_t)r * KSEL + p] = t8i[p];
      topw[(size_t)r * KSEL + p] = t8v[p] / sum;
    }
  }
}

// ---------------------------------------------------------------------------
// k4_scan / k5_emit -- UNCHANGED
// ---------------------------------------------------------------------------
__global__ __launch_bounds__(1024)
void k4_scan(const int* __restrict__ cnt, int* __restrict__ off) {
  __shared__ int part[1024];
  const int t = threadIdx.x;
  int loc[8];
  int s = 0;
#pragma unroll
  for (int i = 0; i < 8; ++i) { loc[i] = s; s += cnt[t * 8 + i]; }
  part[t] = s;
  __syncthreads();
  for (int d = 1; d < 1024; d <<= 1) {
    const int add = (t >= d) ? part[t - d] : 0;
    __syncthreads();
    part[t] += add;
    __syncthreads();
  }
  const int base = (t == 0) ? 0 : part[t - 1];
#pragma unroll
  for (int i = 0; i < 8; ++i) off[t * 8 + i] = base + loc[i];
}

__global__ __launch_bounds__(256)
void k5_emit(const int* __restrict__ topi, const float* __restrict__ topw,
             const int* __restrict__ off, float* __restrict__ out, int E) {
  const int r = blockIdx.x * 256 + threadIdx.x;
  if (r >= NROWS) return;
  const int o = off[r];
  const int sloc = r & (SEQ - 1);
  const int bbase = r & ~(SEQ - 1);
  int e = 0;
#pragma unroll
  for (int p = 0; p < KSEL; ++p) {
    const int id = topi[(size_t)r * KSEL + p];
    const float w = topw[(size_t)r * KSEL + p];
    if (id != sloc) {
      const int pos = o + e;
      if (pos < E) {
        out[pos] = (float)r;
        out[(size_t)E + pos] = (float)(bbase + id);
        out[2 * (size_t)E + pos] = w;
      }
      ++e;
    }
  }
}

// ---------------------------------------------------------------------------
extern "C" void kernel_launch(void* const* d_in, const int* in_sizes, int n_in,
                              void* d_out, int out_size, void* d_ws,
                              size_t ws_size, hipStream_t stream) {
  const float* H = (const float*)d_in[0];      // [4,2048,1024]
  const float* Wphi = (const float*)d_in[1];   // [1024,1024]
  const float* Wpsi = (const float*)d_in[2];   // [1024,1024]
  float* out = (float*)d_out;
  const int E = out_size / 3;

  char* base = (char*)d_ws;
  float* T = (float*)base;                         // 32 MB
  char* regionX = base + 33554432;                 // 4 MB shared region
  float* Wc = (float*)regionX;                     //   Wc (dead after k1)
  unsigned short* cand_v = (unsigned short*)regionX;           // 1 MB used
  unsigned char* cand_i = (unsigned char*)(regionX + 2097152); // 0.5 MB used
  char* pp = regionX + 4194304;
  int* topi = (int*)pp;  pp += 262144;
  float* topw = (float*)pp; pp += 262144;
  int* cnt = (int*)pp;   pp += 32768;
  int* off = (int*)pp;   pp += 32768;
  int* sel = (int*)pp;

  // probe f64-MFMA D layout (writes sel in-stream before any consumer)
  kprobe<<<dim3(1), 64, 0, stream>>>(sel);
  // Wc = Wphi^T * Wpsi  (f64 MFMA, dbuf; vector repair if layout unknown)
  k0_mfma<<<dim3(16, 16), 256, 0, stream>>>(Wphi, Wpsi, Wc, sel);
  k0_repair<<<dim3(16, 16), 256, 0, stream>>>(Wphi, Wpsi, Wc, sel);
  // T = H * Wc  (f64 MFMA, BK=32 dbuf + setprio; vector repair if unknown)
  k1_mfma<<<dim3(8, 64), 256, 0, stream>>>(H, Wc, T, sel);
  k1_repair<<<dim3(8, 64), 256, 0, stream>>>(H, Wc, T, sel);
  // approx MFMA scores, 256^2 tile, dbuf staging, XCD-chunked swizzle
  k2_mfma<<<dim3(8, 8, 4), 512, 0, stream>>>(T, H, cand_v, cand_i);
  // extraction + exact f64 rescore (2 waves/row) + stable top-8 + counts
  kr_rescore<<<dim3(NROWS / 2), 256, 0, stream>>>(T, H, cand_v, cand_i,
                                                  topi, topw, cnt);
  // prefix scan + emit
  k4_scan<<<dim3(1), 1024, 0, stream>>>(cnt, off);
  k5_emit<<<dim3(NROWS / 256), 256, 0, stream>>>(topi, topw, off, out, E);
}

// Round 16
// 542.322 us; speedup vs baseline: 1.0677x; 1.0136x over previous
//
#include <hip/hip_runtime.h>
#include <cmath>

#define SEQ 2048
#define DDIM 1024
#define NROWS 8192   // B*S
#define KSEL 8
#define NCAND 12
#define IMAXC 0x7fffffff

typedef __attribute__((ext_vector_type(8))) short bf16x8;
typedef __attribute__((ext_vector_type(4))) float f32x4;
typedef __attribute__((ext_vector_type(4))) double f64x4;

__device__ __forceinline__ unsigned short f2bf(float f) {
  unsigned u = __builtin_bit_cast(unsigned, f);
  u = (u + 0x7fffu + ((u >> 16) & 1u)) >> 16;
  return (unsigned short)u;
}
__device__ __forceinline__ float bf2f(unsigned short h) {
  unsigned u = ((unsigned)h) << 16;
  return __builtin_bit_cast(float, u);
}
__device__ __forceinline__ unsigned pkbf(float a, float b) {
  unsigned r;
  asm("v_cvt_pk_bf16_f32 %0, %1, %2" : "=v"(r) : "v"(a), "v"(b));
  return r;
}
// D-fragment (row,col) within a 16x16 tile for f64 mfma, by probed layout sel
__device__ __forceinline__ void dmap(int sel, int lg, int lr, int rg,
                                     int& ri, int& ci) {
  switch (sel) {
    case 0:  ri = (lg << 2) + rg; ci = lr; break;
    case 1:  ri = lg + (rg << 2); ci = lr; break;
    case 2:  ri = lr; ci = (lg << 2) + rg; break;
    default: ri = lr; ci = lg + (rg << 2); break;
  }
}

// ---------------------------------------------------------------------------
// probe_sel: per-wave inline determination of the f64-MFMA D layout via
// exact integer arithmetic (order-independent => bitwise equality valid).
// Returns 0..3 (layout) or 4 (unknown -> vector repair path). Wave-uniform,
// deterministic; ~1 MFMA + small integer loop. Replaces the kprobe launch.
// ---------------------------------------------------------------------------
__device__ __forceinline__ int probe_sel() {
  const int lane = threadIdx.x & 63;
  const int lr = lane & 15, lg = lane >> 4;
  const double a = (double)(4 * lr + lg + 1);       // A[r=lr][k=lg]
  const double b = (double)(9 * lr + 5 * lg + 2);   // B[c=lr][k=lg] (asym)
  f64x4 d = (f64x4){0.0, 0.0, 0.0, 0.0};
  d = __builtin_amdgcn_mfma_f64_16x16x4f64(a, b, d, 0, 0, 0);
  int my = 4;
  for (int s = 3; s >= 0; --s) {
    bool ok = true;
    for (int rg = 0; rg < 4; ++rg) {
      int ri, ci;
      dmap(s, lg, lr, rg, ri, ci);
      double e = 0.0;
      for (int k = 0; k < 4; ++k)
        e += (double)(4 * ri + k + 1) * (double)(9 * ci + 5 * k + 2);
      ok = ok && (d[rg] == e);
    }
    if (__all(ok)) my = s;
  }
  return my;
}

// ---------------------------------------------------------------------------
// k0s_mfma: split-K k0. Chunk z sums k in [256z, 256z+256) into f64 partial
// Wp[z] (TN, f64 MFMA, dbuf, 1 barrier/step, 8 steps). Grid (16,16,4).
// ---------------------------------------------------------------------------
#define K0_STAGE(bi)                                        \
  do {                                                      \
    *reinterpret_cast<float4*>(&As[bi][kr][c4]) = pa0;      \
    *reinterpret_cast<float4*>(&As[bi][kr][c4 + 32]) = pa1; \
    *reinterpret_cast<float4*>(&Bs[bi][kr][c4]) = pb0;      \
    *reinterpret_cast<float4*>(&Bs[bi][kr][c4 + 32]) = pb1; \
  } while (0)

__global__ __launch_bounds__(256, 2)
void k0s_mfma(const float* __restrict__ A, const float* __restrict__ B,
              double* __restrict__ Wp) {
  const int sel = probe_sel();
  if (sel >= 4) return;
  __shared__ float As[2][32][72];
  __shared__ float Bs[2][32][72];
  const int tid = threadIdx.x;
  const int lane = tid & 63, w = tid >> 6;
  const int wr = w >> 1, wc = w & 1;
  const int lr = lane & 15, lg = lane >> 4;
  const int brow = blockIdx.y << 6, bcol = blockIdx.x << 6;
  const int z = blockIdx.z;
  const int kr = tid >> 3, c4 = (tid & 7) << 2;

  f64x4 acc[2][2];
#pragma unroll
  for (int mi = 0; mi < 2; ++mi)
#pragma unroll
    for (int nj = 0; nj < 2; ++nj)
      acc[mi][nj] = (f64x4){0.0, 0.0, 0.0, 0.0};

  const float* Ap = &A[(size_t)((z << 8) + kr) * DDIM + brow + c4];
  const float* Bp = &B[(size_t)((z << 8) + kr) * DDIM + bcol + c4];
  float4 pa0 = *reinterpret_cast<const float4*>(Ap);
  float4 pa1 = *reinterpret_cast<const float4*>(Ap + 32);
  float4 pb0 = *reinterpret_cast<const float4*>(Bp);
  float4 pb1 = *reinterpret_cast<const float4*>(Bp + 32);
  K0_STAGE(0);
  {
    const size_t nk = (size_t)32 * DDIM;
    pa0 = *reinterpret_cast<const float4*>(Ap + nk);
    pa1 = *reinterpret_cast<const float4*>(Ap + nk + 32);
    pb0 = *reinterpret_cast<const float4*>(Bp + nk);
    pb1 = *reinterpret_cast<const float4*>(Bp + nk + 32);
  }

  for (int t = 0; t < 8; ++t) {
    __syncthreads();
    const int cur = t & 1;
    if (t < 7) {
      K0_STAGE(cur ^ 1);
      if (t < 6) {
        const size_t nk = (size_t)(t + 2) * 32 * DDIM;
        pa0 = *reinterpret_cast<const float4*>(Ap + nk);
        pa1 = *reinterpret_cast<const float4*>(Ap + nk + 32);
        pb0 = *reinterpret_cast<const float4*>(Bp + nk);
        pb1 = *reinterpret_cast<const float4*>(Bp + nk + 32);
      }
    }
    __builtin_amdgcn_s_setprio(1);
#pragma unroll
    for (int kp = 0; kp < 8; ++kp) {
      const int ka = (kp << 2) + lg;
      double a[2], b[2];
#pragma unroll
      for (int mi = 0; mi < 2; ++mi)
        a[mi] = (double)As[cur][ka][(wr << 5) + (mi << 4) + lr];
#pragma unroll
      for (int nj = 0; nj < 2; ++nj)
        b[nj] = (double)Bs[cur][ka][(wc << 5) + (nj << 4) + lr];
#pragma unroll
      for (int mi = 0; mi < 2; ++mi)
#pragma unroll
        for (int nj = 0; nj < 2; ++nj)
          acc[mi][nj] = __builtin_amdgcn_mfma_f64_16x16x4f64(
              a[mi], b[nj], acc[mi][nj], 0, 0, 0);
    }
    __builtin_amdgcn_s_setprio(0);
  }
  double* Wpz = Wp + ((size_t)z << 20);
#pragma unroll
  for (int mi = 0; mi < 2; ++mi)
#pragma unroll
    for (int nj = 0; nj < 2; ++nj)
#pragma unroll
      for (int rg = 0; rg < 4; ++rg) {
        int ri, ci;
        dmap(sel, lg, lr, rg, ri, ci);
        Wpz[(size_t)(brow + (wr << 5) + (mi << 4) + ri) * DDIM +
            bcol + (wc << 5) + (nj << 4) + ci] = acc[mi][nj][rg];
      }
}

// ---------------------------------------------------------------------------
// k0red: Wc = f32( ((Wp0+Wp1)+Wp2)+Wp3 )  (fixed order, deterministic)
// ---------------------------------------------------------------------------
__global__ __launch_bounds__(256)
void k0red(const double* __restrict__ Wp, float* __restrict__ Wc) {
  if (probe_sel() >= 4) return;
  const size_t i = ((size_t)blockIdx.x * 256 + threadIdx.x) << 1;
  const double2 s0 = *reinterpret_cast<const double2*>(&Wp[i]);
  const double2 s1 = *reinterpret_cast<const double2*>(&Wp[(1u << 20) + i]);
  const double2 s2 = *reinterpret_cast<const double2*>(&Wp[(2u << 20) + i]);
  const double2 s3 = *reinterpret_cast<const double2*>(&Wp[(3u << 20) + i]);
  const double a = ((s0.x + s1.x) + s2.x) + s3.x;
  const double b = ((s0.y + s1.y) + s2.y) + s3.y;
  *reinterpret_cast<float2*>(&Wc[i]) = make_float2((float)a, (float)b);
}

// ---------------------------------------------------------------------------
// k0_mfma: monolithic k0 (R15) -- fallback when ws too small for split-K.
// ---------------------------------------------------------------------------
__global__ __launch_bounds__(256, 2)
void k0_mfma(const float* __restrict__ A, const float* __restrict__ B,
             float* __restrict__ C) {
  const int sel = probe_sel();
  if (sel >= 4) return;
  __shared__ float As[2][32][72];
  __shared__ float Bs[2][32][72];
  const int tid = threadIdx.x;
  const int lane = tid & 63, w = tid >> 6;
  const int wr = w >> 1, wc = w & 1;
  const int lr = lane & 15, lg = lane >> 4;
  const int brow = blockIdx.y << 6, bcol = blockIdx.x << 6;
  const int kr = tid >> 3, c4 = (tid & 7) << 2;

  f64x4 acc[2][2];
#pragma unroll
  for (int mi = 0; mi < 2; ++mi)
#pragma unroll
    for (int nj = 0; nj < 2; ++nj)
      acc[mi][nj] = (f64x4){0.0, 0.0, 0.0, 0.0};

  const float* Ap = &A[(size_t)kr * DDIM + brow + c4];
  const float* Bp = &B[(size_t)kr * DDIM + bcol + c4];
  float4 pa0 = *reinterpret_cast<const float4*>(Ap);
  float4 pa1 = *reinterpret_cast<const float4*>(Ap + 32);
  float4 pb0 = *reinterpret_cast<const float4*>(Bp);
  float4 pb1 = *reinterpret_cast<const float4*>(Bp + 32);
  K0_STAGE(0);
  {
    const size_t nk = (size_t)32 * DDIM;
    pa0 = *reinterpret_cast<const float4*>(Ap + nk);
    pa1 = *reinterpret_cast<const float4*>(Ap + nk + 32);
    pb0 = *reinterpret_cast<const float4*>(Bp + nk);
    pb1 = *reinterpret_cast<const float4*>(Bp + nk + 32);
  }

  for (int t = 0; t < 32; ++t) {
    __syncthreads();
    const int cur = t & 1;
    if (t < 31) {
      K0_STAGE(cur ^ 1);
      if (t < 30) {
        const size_t nk = (size_t)(t + 2) * 32 * DDIM;
        pa0 = *reinterpret_cast<const float4*>(Ap + nk);
        pa1 = *reinterpret_cast<const float4*>(Ap + nk + 32);
        pb0 = *reinterpret_cast<const float4*>(Bp + nk);
        pb1 = *reinterpret_cast<const float4*>(Bp + nk + 32);
      }
    }
    __builtin_amdgcn_s_setprio(1);
#pragma unroll
    for (int kp = 0; kp < 8; ++kp) {
      const int ka = (kp << 2) + lg;
      double a[2], b[2];
#pragma unroll
      for (int mi = 0; mi < 2; ++mi)
        a[mi] = (double)As[cur][ka][(wr << 5) + (mi << 4) + lr];
#pragma unroll
      for (int nj = 0; nj < 2; ++nj)
        b[nj] = (double)Bs[cur][ka][(wc << 5) + (nj << 4) + lr];
#pragma unroll
      for (int mi = 0; mi < 2; ++mi)
#pragma unroll
        for (int nj = 0; nj < 2; ++nj)
          acc[mi][nj] = __builtin_amdgcn_mfma_f64_16x16x4f64(
              a[mi], b[nj], acc[mi][nj], 0, 0, 0);
    }
    __builtin_amdgcn_s_setprio(0);
  }
#pragma unroll
  for (int mi = 0; mi < 2; ++mi)
#pragma unroll
    for (int nj = 0; nj < 2; ++nj)
#pragma unroll
      for (int rg = 0; rg < 4; ++rg) {
        int ri, ci;
        dmap(sel, lg, lr, rg, ri, ci);
        C[(size_t)(brow + (wr << 5) + (mi << 4) + ri) * DDIM +
          bcol + (wc << 5) + (nj << 4) + ci] = (float)acc[mi][nj][rg];
      }
}

// ---------------------------------------------------------------------------
// k0_repair: proven vector-f64 TN kernel; runs only if layout unknown.
// ---------------------------------------------------------------------------
__global__ __launch_bounds__(256)
void k0_repair(const float* __restrict__ A, const float* __restrict__ B,
               float* __restrict__ C) {
  if (probe_sel() < 4) return;
  __shared__ __align__(16) float As[32][68];
  __shared__ __align__(16) float Bs[32][68];
  const int tid = threadIdx.x;
  const int tx = tid & 15, ty = tid >> 4;
  const int brow = blockIdx.y << 6;
  const int bcol = blockIdx.x << 6;
  double acc[4][4] = {};
  for (int k0 = 0; k0 < DDIM; k0 += 32) {
#pragma unroll
    for (int i = 0; i < 2; ++i) {
      const int f = tid + (i << 8);
      const int r = f >> 4;
      const int c4 = (f & 15) << 2;
      *reinterpret_cast<float4*>(&As[r][c4]) =
          *reinterpret_cast<const float4*>(&A[(size_t)(k0 + r) * DDIM + brow + c4]);
      *reinterpret_cast<float4*>(&Bs[r][c4]) =
          *reinterpret_cast<const float4*>(&B[(size_t)(k0 + r) * DDIM + bcol + c4]);
    }
    __syncthreads();
#pragma unroll
    for (int kk = 0; kk < 32; ++kk) {
      const float4 a = *reinterpret_cast<const float4*>(&As[kk][ty << 2]);
      const float4 b = *reinterpret_cast<const float4*>(&Bs[kk][tx << 2]);
      const double ad[4] = {a.x, a.y, a.z, a.w};
      const double bd[4] = {b.x, b.y, b.z, b.w};
#pragma unroll
      for (int i = 0; i < 4; ++i)
#pragma unroll
        for (int j = 0; j < 4; ++j)
          acc[i][j] = fma(ad[i], bd[j], acc[i][j]);
    }
    __syncthreads();
  }
#pragma unroll
  for (int i = 0; i < 4; ++i) {
    float4 v = make_float4((float)acc[i][0], (float)acc[i][1],
                           (float)acc[i][2], (float)acc[i][3]);
    *reinterpret_cast<float4*>(
        &C[(size_t)(brow + (ty << 2) + i) * DDIM + bcol + (tx << 2)]) = v;
  }
}

// ---------------------------------------------------------------------------
// k1_mfma: T = H * Wc (NN, f64 MFMA), BK=32 dbuf + setprio. -- R15 proven,
// sel now probed inline.
// ---------------------------------------------------------------------------
#define K1_STAGE(bi)                                                \
  do {                                                              \
    As[bi][akh + 0][ar] = pa0.x;  As[bi][akh + 1][ar] = pa0.y;      \
    As[bi][akh + 2][ar] = pa0.z;  As[bi][akh + 3][ar] = pa0.w;      \
    As[bi][akh + 4][ar] = pa1.x;  As[bi][akh + 5][ar] = pa1.y;      \
    As[bi][akh + 6][ar] = pa1.z;  As[bi][akh + 7][ar] = pa1.w;      \
    As[bi][akh + 16][ar] = pa2.x; As[bi][akh + 17][ar] = pa2.y;     \
    As[bi][akh + 18][ar] = pa2.z; As[bi][akh + 19][ar] = pa2.w;     \
    As[bi][akh + 20][ar] = pa3.x; As[bi][akh + 21][ar] = pa3.y;     \
    As[bi][akh + 22][ar] = pa3.z; As[bi][akh + 23][ar] = pa3.w;     \
    *reinterpret_cast<float4*>(&Bs[bi][bk][bc4]) = pb0;             \
    *reinterpret_cast<float4*>(&Bs[bi][bk][bc4 + 64]) = pb1;        \
    *reinterpret_cast<float4*>(&Bs[bi][bk + 16][bc4]) = pb2;        \
    *reinterpret_cast<float4*>(&Bs[bi][bk + 16][bc4 + 64]) = pb3;   \
  } while (0)

#define K1_LOAD(koff)                                                        \
  do {                                                                       \
    pa0 = *reinterpret_cast<const float4*>(Ap + (koff));                     \
    pa1 = *reinterpret_cast<const float4*>(Ap + (koff) + 4);                 \
    pa2 = *reinterpret_cast<const float4*>(Ap + (koff) + 16);                \
    pa3 = *reinterpret_cast<const float4*>(Ap + (koff) + 20);                \
    pb0 = *reinterpret_cast<const float4*>(Bp + (size_t)(koff) * DDIM);      \
    pb1 = *reinterpret_cast<const float4*>(Bp + (size_t)(koff) * DDIM + 64); \
    pb2 = *reinterpret_cast<const float4*>(Bp + (size_t)((koff) + 16) * DDIM);      \
    pb3 = *reinterpret_cast<const float4*>(Bp + (size_t)((koff) + 16) * DDIM + 64); \
  } while (0)

__global__ __launch_bounds__(256, 2)
void k1_mfma(const float* __restrict__ A, const float* __restrict__ B,
             float* __restrict__ C) {
  const int sel = probe_sel();
  if (sel >= 4) return;
  __shared__ float As[2][32][144];
  __shared__ float Bs[2][32][144];
  const int tid = threadIdx.x;
  const int lin = blockIdx.y * 8 + blockIdx.x;          // 512 blocks
  const int nlin = (lin & 7) * 64 + (lin >> 3);         // bijective XCD swizzle
  const int brow = (nlin >> 3) << 7;
  const int bcol = (nlin & 7) << 7;
  const int lane = tid & 63, w = tid >> 6;
  const int wr = w >> 1, wc = w & 1;
  const int lr = lane & 15, lg = lane >> 4;
  const int ar = tid >> 1, akh = (tid & 1) << 3;
  const int bk = tid >> 4, bc4 = (tid & 15) << 2;

  f64x4 acc[4][4];
#pragma unroll
  for (int mi = 0; mi < 4; ++mi)
#pragma unroll
    for (int nj = 0; nj < 4; ++nj)
      acc[mi][nj] = (f64x4){0.0, 0.0, 0.0, 0.0};

  const float* Ap = &A[(size_t)(brow + ar) * DDIM + akh];
  const float* Bp = &B[(size_t)bk * DDIM + bcol + bc4];

  float4 pa0, pa1, pa2, pa3, pb0, pb1, pb2, pb3;
  K1_LOAD(0);
  K1_STAGE(0);
  K1_LOAD(32);

  for (int t = 0; t < 32; ++t) {
    __syncthreads();
    const int cur = t & 1;
    if (t < 31) {
      K1_STAGE(cur ^ 1);
      if (t < 30) K1_LOAD((size_t)(t + 2) << 5);
    }
    __builtin_amdgcn_s_setprio(1);
#pragma unroll
    for (int kp = 0; kp < 8; ++kp) {
      const int ka = (kp << 2) + lg;
      double a[4], b[4];
#pragma unroll
      for (int mi = 0; mi < 4; ++mi)
        a[mi] = (double)As[cur][ka][(wr << 6) + (mi << 4) + lr];
#pragma unroll
      for (int nj = 0; nj < 4; ++nj)
        b[nj] = (double)Bs[cur][ka][(wc << 6) + (nj << 4) + lr];
#pragma unroll
      for (int mi = 0; mi < 4; ++mi)
#pragma unroll
        for (int nj = 0; nj < 4; ++nj)
          acc[mi][nj] = __builtin_amdgcn_mfma_f64_16x16x4f64(
              a[mi], b[nj], acc[mi][nj], 0, 0, 0);
    }
    __builtin_amdgcn_s_setprio(0);
  }
#pragma unroll
  for (int mi = 0; mi < 4; ++mi)
#pragma unroll
    for (int nj = 0; nj < 4; ++nj)
#pragma unroll
      for (int rg = 0; rg < 4; ++rg) {
        int ri, ci;
        dmap(sel, lg, lr, rg, ri, ci);
        C[(size_t)(brow + (wr << 6) + (mi << 4) + ri) * DDIM +
          bcol + (wc << 6) + (nj << 4) + ci] = (float)acc[mi][nj][rg];
      }
}

// ---------------------------------------------------------------------------
// k1_repair: proven vector-f64 chain kernel; runs only if layout unknown.
// ---------------------------------------------------------------------------
__global__ __launch_bounds__(256, 2)
void k1_repair(const float* __restrict__ A, const float* __restrict__ B,
               float* __restrict__ C) {
  if (probe_sel() < 4) return;
  __shared__ double As[128][17];
  __shared__ double Bs[16][130];
  const int tid = threadIdx.x;
  const int lin = blockIdx.y * 8 + blockIdx.x;
  const int nlin = (lin & 7) * 64 + (lin >> 3);
  const int brow = (nlin >> 3) << 7;
  const int bcol = (nlin & 7) << 7;
  const int tx = tid & 15, ty = tid >> 4;
  const int ar = tid >> 1, aks = (tid & 1) << 3;
  const int bk = tid >> 4, btx = tid & 15;

  double acc[8][8];
#pragma unroll
  for (int i = 0; i < 8; ++i)
#pragma unroll
    for (int j = 0; j < 8; ++j) acc[i][j] = 0.0;

  const float* Aptr = &A[(size_t)(brow + ar) * DDIM + aks];
  const float* Bptr = &B[(size_t)bk * DDIM + bcol + (btx << 1)];

  float4 pa0, pa1;
  float2 pb[4];
  pa0 = *reinterpret_cast<const float4*>(Aptr);
  pa1 = *reinterpret_cast<const float4*>(Aptr + 4);
#pragma unroll
  for (int w = 0; w < 4; ++w)
    pb[w] = *reinterpret_cast<const float2*>(Bptr + (w << 5));

  for (int k0 = 0; k0 < DDIM; k0 += 16) {
    __syncthreads();
    As[ar][aks + 0] = (double)pa0.x; As[ar][aks + 1] = (double)pa0.y;
    As[ar][aks + 2] = (double)pa0.z; As[ar][aks + 3] = (double)pa0.w;
    As[ar][aks + 4] = (double)pa1.x; As[ar][aks + 5] = (double)pa1.y;
    As[ar][aks + 6] = (double)pa1.z; As[ar][aks + 7] = (double)pa1.w;
#pragma unroll
    for (int w = 0; w < 4; ++w) {
      Bs[bk][(btx << 1) + (w << 5) + 0] = (double)pb[w].x;
      Bs[bk][(btx << 1) + (w << 5) + 1] = (double)pb[w].y;
    }
    __syncthreads();
    if (k0 + 16 < DDIM) {
      pa0 = *reinterpret_cast<const float4*>(Aptr + k0 + 16);
      pa1 = *reinterpret_cast<const float4*>(Aptr + k0 + 20);
#pragma unroll
      for (int w = 0; w < 4; ++w)
        pb[w] = *reinterpret_cast<const float2*>(
            Bptr + (size_t)(k0 + 16) * DDIM + (w << 5));
    }
#pragma unroll 8
    for (int kk = 0; kk < 16; ++kk) {
      double a[8];
      double2 b[4];
#pragma unroll
      for (int i = 0; i < 8; ++i) a[i] = As[(ty << 3) + i][kk];
#pragma unroll
      for (int jj = 0; jj < 4; ++jj)
        b[jj] = *reinterpret_cast<const double2*>(&Bs[kk][(tx << 1) + (jj << 5)]);
#pragma unroll
      for (int i = 0; i < 8; ++i) {
#pragma unroll
        for (int jj = 0; jj < 4; ++jj) {
          acc[i][(jj << 1) + 0] = fma(a[i], b[jj].x, acc[i][(jj << 1) + 0]);
          acc[i][(jj << 1) + 1] = fma(a[i], b[jj].y, acc[i][(jj << 1) + 1]);
        }
      }
    }
  }
#pragma unroll
  for (int i = 0; i < 8; ++i) {
    float* crow = &C[(size_t)(brow + (ty << 3) + i) * DDIM + bcol + (tx << 1)];
#pragma unroll
    for (int jj = 0; jj < 4; ++jj) {
      float2 v = make_float2((float)acc[i][(jj << 1)],
                             (float)acc[i][(jj << 1) + 1]);
      *reinterpret_cast<float2*>(crow + (jj << 5)) = v;
    }
  }
}

// ---------------------------------------------------------------------------
// k2_mfma: approx scores, 256x256 tile, 512 threads, dbuf staging,
// XCD-chunked swizzle. -- UNCHANGED (R14/R15)
// ---------------------------------------------------------------------------
#define K2_LOAD(koff)                                                         \
  do {                                                                        \
    _Pragma("unroll")                                                         \
    for (int q = 0; q < 4; ++q) {                                             \
      const int c = (q << 9) + tid;                                           \
      const int row = c >> 3;                                                 \
      const int gs = (c & 7) ^ (row & 7);                                     \
      const float* sT = &T[(size_t)(row0g + row) * DDIM + (koff) + (gs << 3)];\
      rT[2 * q] = *reinterpret_cast<const float4*>(sT);                       \
      rT[2 * q + 1] = *reinterpret_cast<const float4*>(sT + 4);               \
      const float* sH = &H[(size_t)(col0g + row) * DDIM + (koff) + (gs << 3)];\
      rH[2 * q] = *reinterpret_cast<const float4*>(sH);                       \
      rH[2 * q + 1] = *reinterpret_cast<const float4*>(sH + 4);               \
    }                                                                         \
  } while (0)

#define K2_STAGE(bi)                                                          \
  do {                                                                        \
    _Pragma("unroll")                                                         \
    for (int q = 0; q < 4; ++q) {                                             \
      const int c = (q << 9) + tid;                                           \
      uint4 o;                                                                \
      o.x = pkbf(rT[2 * q].x, rT[2 * q].y);                                   \
      o.y = pkbf(rT[2 * q].z, rT[2 * q].w);                                   \
      o.z = pkbf(rT[2 * q + 1].x, rT[2 * q + 1].y);                           \
      o.w = pkbf(rT[2 * q + 1].z, rT[2 * q + 1].w);                           \
      *reinterpret_cast<uint4*>(&u.stage[bi][0][c << 3]) = o;                 \
      uint4 o2;                                                               \
      o2.x = pkbf(rH[2 * q].x, rH[2 * q].y);                                  \
      o2.y = pkbf(rH[2 * q].z, rH[2 * q].w);                                  \
      o2.z = pkbf(rH[2 * q + 1].x, rH[2 * q + 1].y);                          \
      o2.w = pkbf(rH[2 * q + 1].z, rH[2 * q + 1].w);                          \
      *reinterpret_cast<uint4*>(&u.stage[bi][1][c << 3]) = o2;                \
    }                                                                         \
  } while (0)

__global__ __launch_bounds__(512, 1)
void k2_mfma(const float* __restrict__ T, const float* __restrict__ H,
             unsigned short* __restrict__ cand_v,
             unsigned char* __restrict__ cand_i) {
  __shared__ union {
    unsigned short stage[2][2][256 * 64];   // 128 KB (dbuf x {T,H})
    float Sl[64][264];                      // 67.6 KB
    struct {
      float mv[512][8];
      unsigned char mi[512][8];
    } mg;
  } u;
  const int tid = threadIdx.x;
  const int lane = tid & 63;
  const int w = tid >> 6;               // 0..7
  const int wr = w >> 2, wc = w & 3;    // 2 x 4 wave grid
  const int lr = lane & 15, lg = lane >> 4;
  const int lin = blockIdx.z * 64 + blockIdx.y * 8 + blockIdx.x;
  const int nl = (lin & 7) * 32 + (lin >> 3);
  const int bx = nl & 7;                // col block 0..7
  const int by = (nl >> 3) & 7;         // row block 0..7
  const int z = nl >> 6;                // batch 0..3
  const int brow = by << 8, bcol = bx << 8;
  const int row0g = z * SEQ + brow;
  const int col0g = z * SEQ + bcol;

  f32x4 acc[8][4];
#pragma unroll
  for (int mi = 0; mi < 8; ++mi)
#pragma unroll
    for (int nj = 0; nj < 4; ++nj)
      acc[mi][nj] = (f32x4){0.f, 0.f, 0.f, 0.f};

  float4 rT[8], rH[8];
  K2_LOAD(0);
  K2_STAGE(0);
  K2_LOAD(64);

  for (int t = 0; t < 16; ++t) {
    __syncthreads();
    const int cur = t & 1;
    if (t < 15) {
      K2_STAGE(cur ^ 1);
      if (t < 14) K2_LOAD((t + 2) << 6);
    }
#pragma unroll
    for (int kh2 = 0; kh2 < 2; ++kh2) {
      const int sl = (kh2 << 2) + lg;
      bf16x8 bfv[4];
#pragma unroll
      for (int nj = 0; nj < 4; ++nj) {
        const int rb = (wc << 6) + (nj << 4) + lr;
        bfv[nj] = *reinterpret_cast<const bf16x8*>(
            &u.stage[cur][1][(rb << 6) + ((sl ^ (rb & 7)) << 3)]);
      }
#pragma unroll
      for (int mi = 0; mi < 8; ++mi) {
        const int ra = (wr << 7) + (mi << 4) + lr;
        const bf16x8 af = *reinterpret_cast<const bf16x8*>(
            &u.stage[cur][0][(ra << 6) + ((sl ^ (ra & 7)) << 3)]);
#pragma unroll
        for (int nj = 0; nj < 4; ++nj)
          acc[mi][nj] = __builtin_amdgcn_mfma_f32_16x16x32_bf16(
              af, bfv[nj], acc[mi][nj], 0, 0, 0);
      }
    }
  }

  // epilogue: 4 phases of 64 rows (unchanged)
  const int srow = tid >> 3;     // 0..63
  const int qd = tid & 7;        // eighth (32 cols each)
#pragma unroll
  for (int p = 0; p < 4; ++p) {
    __syncthreads();
    if (wr == (p >> 1)) {
      const int mib = (p & 1) << 2;
#pragma unroll
      for (int mi2 = 0; mi2 < 4; ++mi2)
#pragma unroll
        for (int nj = 0; nj < 4; ++nj)
#pragma unroll
          for (int rg = 0; rg < 4; ++rg)
            u.Sl[(mi2 << 4) + (lg << 2) + rg][(wc << 6) + (nj << 4) + lr] =
                acc[mib + mi2][nj][rg];
    }
    __syncthreads();
    float v[KSEL];
    int ci[KSEL];
#pragma unroll
    for (int s = 0; s < KSEL; ++s) { v[s] = -3.0e38f; ci[s] = 0; }
    const int c0 = qd << 5;
    for (int c = 0; c < 32; ++c) {
      const float x = u.Sl[srow][c0 + c];
      if (x > v[KSEL - 1]) {
        float pv = x; int pc = c0 + c;
#pragma unroll
        for (int s = 0; s < KSEL; ++s) {
          if (x > v[s]) {
            const float tv = v[s]; const int tc = ci[s];
            v[s] = pv; ci[s] = pc; pv = tv; pc = tc;
          }
        }
      }
    }
    __syncthreads();   // all Sl reads done before mg overlay
#pragma unroll
    for (int s = 0; s < KSEL; ++s) {
      u.mg.mv[tid][s] = v[s];
      u.mg.mi[tid][s] = (unsigned char)ci[s];
    }
    __syncthreads();
    if (qd == 0) {
      float fv[KSEL];
      int fi[KSEL];
#pragma unroll
      for (int s = 0; s < KSEL; ++s) { fv[s] = -3.0e38f; fi[s] = 0; }
#pragma unroll
      for (int t2 = 0; t2 < 8; ++t2) {
#pragma unroll
        for (int s = 0; s < KSEL; ++s) {
          const float x = u.mg.mv[tid + t2][s];
          const int idx = u.mg.mi[tid + t2][s];
          if (x > fv[KSEL - 1]) {
            float pv = x; int pc = idx;
#pragma unroll
            for (int s2 = 0; s2 < KSEL; ++s2) {
              if (x > fv[s2]) {
                const float tv = fv[s2]; const int tc = fi[s2];
                fv[s2] = pv; fi[s2] = pc; pv = tv; pc = tc;
              }
            }
          }
        }
      }
      const size_t base =
          (size_t)(row0g + (p << 6) + srow) * 64 + ((size_t)bx << 3);
#pragma unroll
      for (int s = 0; s < KSEL; ++s) {
        cand_v[base + s] = f2bf(fv[s]);
        cand_i[base + s] = (unsigned char)fi[s];
      }
    }
  }
}

// ---------------------------------------------------------------------------
// kr_rescore -- UNCHANGED (R12: 2 rows/block, 2 waves/row, NCAND=12)
// ---------------------------------------------------------------------------
__global__ __launch_bounds__(256)
void kr_rescore(const float* __restrict__ T, const float* __restrict__ H,
                const unsigned short* __restrict__ cand_v,
                const unsigned char* __restrict__ cand_i,
                int* __restrict__ topi, float* __restrict__ topw,
                int* __restrict__ cnt) {
  __shared__ float smv[2][2][KSEL];
  __shared__ int smi[2][2][KSEL];
  const int tid = threadIdx.x, lane = tid & 63, w = tid >> 6;
  const int rl = w >> 1;
  const int half = w & 1;
  const int r = blockIdx.x * 2 + rl;
  const int b = r >> 11, iloc = r & (SEQ - 1);

  const size_t cbase = (size_t)r * 64;
  float v0 = bf2f(cand_v[cbase + lane]);
  int i0 = ((lane >> 3) << 8) + cand_i[cbase + lane];
  int keep = 0;
  for (int rnd = 0; rnd < NCAND; ++rnd) {
    float m = v0;
#pragma unroll
    for (int off = 32; off >= 1; off >>= 1) m = fmaxf(m, __shfl_xor(m, off));
    const unsigned long long bm = __ballot(v0 == m);
    const int owner = __ffsll(bm) - 1;
    const int oi = __shfl(i0, owner);
    if (lane == owner) v0 = -3.0e38f;
    if (lane == rnd) keep = oi;
  }

  const float* Trow = T + (size_t)r * DDIM;
  float4 t4[4];
#pragma unroll
  for (int q = 0; q < 4; ++q)
    t4[q] = *reinterpret_cast<const float4*>(&Trow[(q << 8) + (lane << 2)]);

  float t8v[KSEL];
  int t8i[KSEL];
#pragma unroll
  for (int p = 0; p < KSEL; ++p) { t8v[p] = -1.0f; t8i[p] = IMAXC; }

  const int c0 = half * (NCAND / 2);
  for (int c = c0; c < c0 + NCAND / 2; ++c) {
    const int j = __shfl(keep, c);
    const float* Hrow = H + ((size_t)(b << 11) + j) * DDIM;
    double s = 0.0;
#pragma unroll
    for (int q = 0; q < 4; ++q) {
      const float4 h = *reinterpret_cast<const float4*>(&Hrow[(q << 8) + (lane << 2)]);
      s = fma((double)t4[q].x, (double)h.x, s);
      s = fma((double)t4[q].y, (double)h.y, s);
      s = fma((double)t4[q].z, (double)h.z, s);
      s = fma((double)t4[q].w, (double)h.w, s);
    }
#pragma unroll
    for (int off = 1; off < 64; off <<= 1) s += __shfl_xor(s, off);
    const float aff = expf((float)s);
    const bool g7 = (aff > t8v[KSEL - 1]) ||
                    (aff == t8v[KSEL - 1] && j < t8i[KSEL - 1]);
    if (g7) {
      float pv = aff; int pi = j;
#pragma unroll
      for (int p = 0; p < KSEL; ++p) {
        const bool g = (aff > t8v[p]) || (aff == t8v[p] && j < t8i[p]);
        if (g) {
          const float tv = t8v[p]; const int ti = t8i[p];
          t8v[p] = pv; t8i[p] = pi; pv = tv; pi = ti;
        }
      }
    }
  }

  if (lane == 0) {
#pragma unroll
    for (int p = 0; p < KSEL; ++p) {
      smv[rl][half][p] = t8v[p];
      smi[rl][half][p] = t8i[p];
    }
  }
  __syncthreads();
  if (half == 0 && lane == 0) {
#pragma unroll
    for (int p = 0; p < KSEL; ++p) {
      const float x = smv[rl][1][p];
      const int jx = smi[rl][1][p];
      const bool g7 = (x > t8v[KSEL - 1]) ||
                      (x == t8v[KSEL - 1] && jx < t8i[KSEL - 1]);
      if (g7) {
        float pv = x; int pi = jx;
#pragma unroll
        for (int q = 0; q < KSEL; ++q) {
          const bool g = (x > t8v[q]) || (x == t8v[q] && jx < t8i[q]);
          if (g) {
            const float tv = t8v[q]; const int ti = t8i[q];
            t8v[q] = pv; t8i[q] = pi; pv = tv; pi = ti;
          }
        }
      }
    }
    float sum = 0.0f;
#pragma unroll
    for (int p = 0; p < KSEL; ++p) sum += t8v[p];
    sum += 1e-8f;
    int c8 = KSEL;
#pragma unroll
    for (int p = 0; p < KSEL; ++p)
      if (t8i[p] == iloc) --c8;
    cnt[r] = c8;
#pragma unroll
    for (int p = 0; p < KSEL; ++p) {
      topi[(size_t)r * KSEL + p] = t8i[p];
      topw[(size_t)r * KSEL + p] = t8v[p] / sum;
    }
  }
}

// ---------------------------------------------------------------------------
// k4_scan / k5_emit -- UNCHANGED
// ---------------------------------------------------------------------------
__global__ __launch_bounds__(1024)
void k4_scan(const int* __restrict__ cnt, int* __restrict__ off) {
  __shared__ int part[1024];
  const int t = threadIdx.x;
  int loc[8];
  int s = 0;
#pragma unroll
  for (int i = 0; i < 8; ++i) { loc[i] = s; s += cnt[t * 8 + i]; }
  part[t] = s;
  __syncthreads();
  for (int d = 1; d < 1024; d <<= 1) {
    const int add = (t >= d) ? part[t - d] : 0;
    __syncthreads();
    part[t] += add;
    __syncthreads();
  }
  const int base = (t == 0) ? 0 : part[t - 1];
#pragma unroll
  for (int i = 0; i < 8; ++i) off[t * 8 + i] = base + loc[i];
}

__global__ __launch_bounds__(256)
void k5_emit(const int* __restrict__ topi, const float* __restrict__ topw,
             const int* __restrict__ off, float* __restrict__ out, int E) {
  const int r = blockIdx.x * 256 + threadIdx.x;
  if (r >= NROWS) return;
  const int o = off[r];
  const int sloc = r & (SEQ - 1);
  const int bbase = r & ~(SEQ - 1);
  int e = 0;
#pragma unroll
  for (int p = 0; p < KSEL; ++p) {
    const int id = topi[(size_t)r * KSEL + p];
    const float w = topw[(size_t)r * KSEL + p];
    if (id != sloc) {
      const int pos = o + e;
      if (pos < E) {
        out[pos] = (float)r;
        out[(size_t)E + pos] = (float)(bbase + id);
        out[2 * (size_t)E + pos] = w;
      }
      ++e;
    }
  }
}

// ---------------------------------------------------------------------------
extern "C" void kernel_launch(void* const* d_in, const int* in_sizes, int n_in,
                              void* d_out, int out_size, void* d_ws,
                              size_t ws_size, hipStream_t stream) {
  const float* H = (const float*)d_in[0];      // [4,2048,1024]
  const float* Wphi = (const float*)d_in[1];   // [1024,1024]
  const float* Wpsi = (const float*)d_in[2];   // [1024,1024]
  float* out = (float*)d_out;
  const int E = out_size / 3;

  char* base = (char*)d_ws;
  float* T = (float*)base;                         // 32 MB
  char* regionX = base + 33554432;                 // 4 MB shared region
  float* Wc = (float*)regionX;                     //   Wc (dead after k1)
  unsigned short* cand_v = (unsigned short*)regionX;           // 1 MB used
  unsigned char* cand_i = (unsigned char*)(regionX + 2097152); // 0.5 MB used
  char* pp = regionX + 4194304;
  int* topi = (int*)pp;  pp += 262144;
  float* topw = (float*)pp; pp += 262144;
  int* cnt = (int*)pp;   pp += 32768;
  int* off = (int*)pp;   pp += 32768;   // pp now at base+38338560

  // split-K partials: 4 x 8 MB f64 at base+38338560 .. base+71892992
  double* Wp = (double*)(base + 38338560);
  const size_t NEED_SPLITK = 71892992;  // R13 proved ws >= 72.35 MB
  const bool splitk = (ws_size >= NEED_SPLITK);

  // Wc = Wphi^T * Wpsi  (f64 MFMA; split-K if ws allows; vector repair if
  // layout unknown — all kernels self-probe the D layout, no kprobe launch)
  if (splitk) {
    k0s_mfma<<<dim3(16, 16, 4), 256, 0, stream>>>(Wphi, Wpsi, Wp);
    k0red<<<dim3(2048), 256, 0, stream>>>(Wp, Wc);
  } else {
    k0_mfma<<<dim3(16, 16), 256, 0, stream>>>(Wphi, Wpsi, Wc);
  }
  k0_repair<<<dim3(16, 16), 256, 0, stream>>>(Wphi, Wpsi, Wc);
  // T = H * Wc  (f64 MFMA, BK=32 dbuf + setprio; vector repair if unknown)
  k1_mfma<<<dim3(8, 64), 256, 0, stream>>>(H, Wc, T);
  k1_repair<<<dim3(8, 64), 256, 0, stream>>>(H, Wc, T);
  // approx MFMA scores, 256^2 tile, dbuf staging, XCD-chunked swizzle
  k2_mfma<<<dim3(8, 8, 4), 512, 0, stream>>>(T, H, cand_v, cand_i);
  // extraction + exact f64 rescore (2 waves/row) + stable top-8 + counts
  kr_rescore<<<dim3(NROWS / 2), 256, 0, stream>>>(T, H, cand_v, cand_i,
                                                  topi, topw, cnt);
  // prefix scan + emit
  k4_scan<<<dim3(1), 1024, 0, stream>>>(cnt, off);
  k5_emit<<<dim3(NROWS / 256), 256, 0, stream>>>(topi, topw, off, out, E);
}

// Round 17
// 531.573 us; speedup vs baseline: 1.0893x; 1.0202x over previous
//
#include <hip/hip_runtime.h>
#include <cmath>

#define SEQ 2048
#define DDIM 1024
#define NROWS 8192   // B*S
#define KSEL 8
#define NCAND 12
#define IMAXC 0x7fffffff

typedef __attribute__((ext_vector_type(8))) short bf16x8;
typedef __attribute__((ext_vector_type(4))) float f32x4;
typedef __attribute__((ext_vector_type(4))) double f64x4;

__device__ __forceinline__ unsigned short f2bf(float f) {
  unsigned u = __builtin_bit_cast(unsigned, f);
  u = (u + 0x7fffu + ((u >> 16) & 1u)) >> 16;
  return (unsigned short)u;
}
__device__ __forceinline__ float bf2f(unsigned short h) {
  unsigned u = ((unsigned)h) << 16;
  return __builtin_bit_cast(float, u);
}
__device__ __forceinline__ unsigned pkbf(float a, float b) {
  unsigned r;
  asm("v_cvt_pk_bf16_f32 %0, %1, %2" : "=v"(r) : "v"(a), "v"(b));
  return r;
}
// D-fragment (row,col) within a 16x16 tile for f64 mfma, by probed layout sel
__device__ __forceinline__ void dmap(int sel, int lg, int lr, int rg,
                                     int& ri, int& ci) {
  switch (sel) {
    case 0:  ri = (lg << 2) + rg; ci = lr; break;
    case 1:  ri = lg + (rg << 2); ci = lr; break;
    case 2:  ri = lr; ci = (lg << 2) + rg; break;
    default: ri = lr; ci = lg + (rg << 2); break;
  }
}

// ---------------------------------------------------------------------------
// probe_sel: per-wave inline determination of the f64-MFMA D layout via
// exact integer arithmetic. 0..3 layout; 4 -> unknown (vector repair path).
// ---------------------------------------------------------------------------
__device__ __forceinline__ int probe_sel() {
  const int lane = threadIdx.x & 63;
  const int lr = lane & 15, lg = lane >> 4;
  const double a = (double)(4 * lr + lg + 1);
  const double b = (double)(9 * lr + 5 * lg + 2);
  f64x4 d = (f64x4){0.0, 0.0, 0.0, 0.0};
  d = __builtin_amdgcn_mfma_f64_16x16x4f64(a, b, d, 0, 0, 0);
  int my = 4;
  for (int s = 3; s >= 0; --s) {
    bool ok = true;
    for (int rg = 0; rg < 4; ++rg) {
      int ri, ci;
      dmap(s, lg, lr, rg, ri, ci);
      double e = 0.0;
      for (int k = 0; k < 4; ++k)
        e += (double)(4 * ri + k + 1) * (double)(9 * ci + 5 * k + 2);
      ok = ok && (d[rg] == e);
    }
    if (__all(ok)) my = s;
  }
  return my;
}

// ---------------------------------------------------------------------------
// k0s_mfma: split-K k0 (4 chunks -> f64 partials). -- UNCHANGED (R16)
// ---------------------------------------------------------------------------
#define K0_STAGE(bi)                                        \
  do {                                                      \
    *reinterpret_cast<float4*>(&As[bi][kr][c4]) = pa0;      \
    *reinterpret_cast<float4*>(&As[bi][kr][c4 + 32]) = pa1; \
    *reinterpret_cast<float4*>(&Bs[bi][kr][c4]) = pb0;      \
    *reinterpret_cast<float4*>(&Bs[bi][kr][c4 + 32]) = pb1; \
  } while (0)

__global__ __launch_bounds__(256, 2)
void k0s_mfma(const float* __restrict__ A, const float* __restrict__ B,
              double* __restrict__ Wp) {
  const int sel = probe_sel();
  if (sel >= 4) return;
  __shared__ float As[2][32][72];
  __shared__ float Bs[2][32][72];
  const int tid = threadIdx.x;
  const int lane = tid & 63, w = tid >> 6;
  const int wr = w >> 1, wc = w & 1;
  const int lr = lane & 15, lg = lane >> 4;
  const int brow = blockIdx.y << 6, bcol = blockIdx.x << 6;
  const int z = blockIdx.z;
  const int kr = tid >> 3, c4 = (tid & 7) << 2;

  f64x4 acc[2][2];
#pragma unroll
  for (int mi = 0; mi < 2; ++mi)
#pragma unroll
    for (int nj = 0; nj < 2; ++nj)
      acc[mi][nj] = (f64x4){0.0, 0.0, 0.0, 0.0};

  const float* Ap = &A[(size_t)((z << 8) + kr) * DDIM + brow + c4];
  const float* Bp = &B[(size_t)((z << 8) + kr) * DDIM + bcol + c4];
  float4 pa0 = *reinterpret_cast<const float4*>(Ap);
  float4 pa1 = *reinterpret_cast<const float4*>(Ap + 32);
  float4 pb0 = *reinterpret_cast<const float4*>(Bp);
  float4 pb1 = *reinterpret_cast<const float4*>(Bp + 32);
  K0_STAGE(0);
  {
    const size_t nk = (size_t)32 * DDIM;
    pa0 = *reinterpret_cast<const float4*>(Ap + nk);
    pa1 = *reinterpret_cast<const float4*>(Ap + nk + 32);
    pb0 = *reinterpret_cast<const float4*>(Bp + nk);
    pb1 = *reinterpret_cast<const float4*>(Bp + nk + 32);
  }

  for (int t = 0; t < 8; ++t) {
    __syncthreads();
    const int cur = t & 1;
    if (t < 7) {
      K0_STAGE(cur ^ 1);
      if (t < 6) {
        const size_t nk = (size_t)(t + 2) * 32 * DDIM;
        pa0 = *reinterpret_cast<const float4*>(Ap + nk);
        pa1 = *reinterpret_cast<const float4*>(Ap + nk + 32);
        pb0 = *reinterpret_cast<const float4*>(Bp + nk);
        pb1 = *reinterpret_cast<const float4*>(Bp + nk + 32);
      }
    }
    __builtin_amdgcn_s_setprio(1);
#pragma unroll
    for (int kp = 0; kp < 8; ++kp) {
      const int ka = (kp << 2) + lg;
      double a[2], b[2];
#pragma unroll
      for (int mi = 0; mi < 2; ++mi)
        a[mi] = (double)As[cur][ka][(wr << 5) + (mi << 4) + lr];
#pragma unroll
      for (int nj = 0; nj < 2; ++nj)
        b[nj] = (double)Bs[cur][ka][(wc << 5) + (nj << 4) + lr];
#pragma unroll
      for (int mi = 0; mi < 2; ++mi)
#pragma unroll
        for (int nj = 0; nj < 2; ++nj)
          acc[mi][nj] = __builtin_amdgcn_mfma_f64_16x16x4f64(
              a[mi], b[nj], acc[mi][nj], 0, 0, 0);
    }
    __builtin_amdgcn_s_setprio(0);
  }
  double* Wpz = Wp + ((size_t)z << 20);
#pragma unroll
  for (int mi = 0; mi < 2; ++mi)
#pragma unroll
    for (int nj = 0; nj < 2; ++nj)
#pragma unroll
      for (int rg = 0; rg < 4; ++rg) {
        int ri, ci;
        dmap(sel, lg, lr, rg, ri, ci);
        Wpz[(size_t)(brow + (wr << 5) + (mi << 4) + ri) * DDIM +
            bcol + (wc << 5) + (nj << 4) + ci] = acc[mi][nj][rg];
      }
}

// ---------------------------------------------------------------------------
// k0red: Wc = f32( ((Wp0+Wp1)+Wp2)+Wp3 ). -- UNCHANGED
// ---------------------------------------------------------------------------
__global__ __launch_bounds__(256)
void k0red(const double* __restrict__ Wp, float* __restrict__ Wc) {
  if (probe_sel() >= 4) return;
  const size_t i = ((size_t)blockIdx.x * 256 + threadIdx.x) << 1;
  const double2 s0 = *reinterpret_cast<const double2*>(&Wp[i]);
  const double2 s1 = *reinterpret_cast<const double2*>(&Wp[(1u << 20) + i]);
  const double2 s2 = *reinterpret_cast<const double2*>(&Wp[(2u << 20) + i]);
  const double2 s3 = *reinterpret_cast<const double2*>(&Wp[(3u << 20) + i]);
  const double a = ((s0.x + s1.x) + s2.x) + s3.x;
  const double b = ((s0.y + s1.y) + s2.y) + s3.y;
  *reinterpret_cast<float2*>(&Wc[i]) = make_float2((float)a, (float)b);
}

// ---------------------------------------------------------------------------
// k0_mfma: monolithic k0 -- fallback when ws too small for split-K. -- UNCHANGED
// ---------------------------------------------------------------------------
__global__ __launch_bounds__(256, 2)
void k0_mfma(const float* __restrict__ A, const float* __restrict__ B,
             float* __restrict__ C) {
  const int sel = probe_sel();
  if (sel >= 4) return;
  __shared__ float As[2][32][72];
  __shared__ float Bs[2][32][72];
  const int tid = threadIdx.x;
  const int lane = tid & 63, w = tid >> 6;
  const int wr = w >> 1, wc = w & 1;
  const int lr = lane & 15, lg = lane >> 4;
  const int brow = blockIdx.y << 6, bcol = blockIdx.x << 6;
  const int kr = tid >> 3, c4 = (tid & 7) << 2;

  f64x4 acc[2][2];
#pragma unroll
  for (int mi = 0; mi < 2; ++mi)
#pragma unroll
    for (int nj = 0; nj < 2; ++nj)
      acc[mi][nj] = (f64x4){0.0, 0.0, 0.0, 0.0};

  const float* Ap = &A[(size_t)kr * DDIM + brow + c4];
  const float* Bp = &B[(size_t)kr * DDIM + bcol + c4];
  float4 pa0 = *reinterpret_cast<const float4*>(Ap);
  float4 pa1 = *reinterpret_cast<const float4*>(Ap + 32);
  float4 pb0 = *reinterpret_cast<const float4*>(Bp);
  float4 pb1 = *reinterpret_cast<const float4*>(Bp + 32);
  K0_STAGE(0);
  {
    const size_t nk = (size_t)32 * DDIM;
    pa0 = *reinterpret_cast<const float4*>(Ap + nk);
    pa1 = *reinterpret_cast<const float4*>(Ap + nk + 32);
    pb0 = *reinterpret_cast<const float4*>(Bp + nk);
    pb1 = *reinterpret_cast<const float4*>(Bp + nk + 32);
  }

  for (int t = 0; t < 32; ++t) {
    __syncthreads();
    const int cur = t & 1;
    if (t < 31) {
      K0_STAGE(cur ^ 1);
      if (t < 30) {
        const size_t nk = (size_t)(t + 2) * 32 * DDIM;
        pa0 = *reinterpret_cast<const float4*>(Ap + nk);
        pa1 = *reinterpret_cast<const float4*>(Ap + nk + 32);
        pb0 = *reinterpret_cast<const float4*>(Bp + nk);
        pb1 = *reinterpret_cast<const float4*>(Bp + nk + 32);
      }
    }
    __builtin_amdgcn_s_setprio(1);
#pragma unroll
    for (int kp = 0; kp < 8; ++kp) {
      const int ka = (kp << 2) + lg;
      double a[2], b[2];
#pragma unroll
      for (int mi = 0; mi < 2; ++mi)
        a[mi] = (double)As[cur][ka][(wr << 5) + (mi << 4) + lr];
#pragma unroll
      for (int nj = 0; nj < 2; ++nj)
        b[nj] = (double)Bs[cur][ka][(wc << 5) + (nj << 4) + lr];
#pragma unroll
      for (int mi = 0; mi < 2; ++mi)
#pragma unroll
        for (int nj = 0; nj < 2; ++nj)
          acc[mi][nj] = __builtin_amdgcn_mfma_f64_16x16x4f64(
              a[mi], b[nj], acc[mi][nj], 0, 0, 0);
    }
    __builtin_amdgcn_s_setprio(0);
  }
#pragma unroll
  for (int mi = 0; mi < 2; ++mi)
#pragma unroll
    for (int nj = 0; nj < 2; ++nj)
#pragma unroll
      for (int rg = 0; rg < 4; ++rg) {
        int ri, ci;
        dmap(sel, lg, lr, rg, ri, ci);
        C[(size_t)(brow + (wr << 5) + (mi << 4) + ri) * DDIM +
          bcol + (wc << 5) + (nj << 4) + ci] = (float)acc[mi][nj][rg];
      }
}

// ---------------------------------------------------------------------------
// k0_repair: proven vector-f64 TN kernel; runs only if layout unknown. -- UNCHANGED
// ---------------------------------------------------------------------------
__global__ __launch_bounds__(256)
void k0_repair(const float* __restrict__ A, const float* __restrict__ B,
               float* __restrict__ C) {
  if (probe_sel() < 4) return;
  __shared__ __align__(16) float As[32][68];
  __shared__ __align__(16) float Bs[32][68];
  const int tid = threadIdx.x;
  const int tx = tid & 15, ty = tid >> 4;
  const int brow = blockIdx.y << 6;
  const int bcol = blockIdx.x << 6;
  double acc[4][4] = {};
  for (int k0 = 0; k0 < DDIM; k0 += 32) {
#pragma unroll
    for (int i = 0; i < 2; ++i) {
      const int f = tid + (i << 8);
      const int r = f >> 4;
      const int c4 = (f & 15) << 2;
      *reinterpret_cast<float4*>(&As[r][c4]) =
          *reinterpret_cast<const float4*>(&A[(size_t)(k0 + r) * DDIM + brow + c4]);
      *reinterpret_cast<float4*>(&Bs[r][c4]) =
          *reinterpret_cast<const float4*>(&B[(size_t)(k0 + r) * DDIM + bcol + c4]);
    }
    __syncthreads();
#pragma unroll
    for (int kk = 0; kk < 32; ++kk) {
      const float4 a = *reinterpret_cast<const float4*>(&As[kk][ty << 2]);
      const float4 b = *reinterpret_cast<const float4*>(&Bs[kk][tx << 2]);
      const double ad[4] = {a.x, a.y, a.z, a.w};
      const double bd[4] = {b.x, b.y, b.z, b.w};
#pragma unroll
      for (int i = 0; i < 4; ++i)
#pragma unroll
        for (int j = 0; j < 4; ++j)
          acc[i][j] = fma(ad[i], bd[j], acc[i][j]);
    }
    __syncthreads();
  }
#pragma unroll
  for (int i = 0; i < 4; ++i) {
    float4 v = make_float4((float)acc[i][0], (float)acc[i][1],
                           (float)acc[i][2], (float)acc[i][3]);
    *reinterpret_cast<float4*>(
        &C[(size_t)(brow + (ty << 2) + i) * DDIM + bcol + (tx << 2)]) = v;
  }
}

// ---------------------------------------------------------------------------
// k1_mfma: T = H * Wc (NN, f64 MFMA), BK=32 dbuf + setprio. -- UNCHANGED (R15/16)
// ---------------------------------------------------------------------------
#define K1_STAGE(bi)                                                \
  do {                                                              \
    As[bi][akh + 0][ar] = pa0.x;  As[bi][akh + 1][ar] = pa0.y;      \
    As[bi][akh + 2][ar] = pa0.z;  As[bi][akh + 3][ar] = pa0.w;      \
    As[bi][akh + 4][ar] = pa1.x;  As[bi][akh + 5][ar] = pa1.y;      \
    As[bi][akh + 6][ar] = pa1.z;  As[bi][akh + 7][ar] = pa1.w;      \
    As[bi][akh + 16][ar] = pa2.x; As[bi][akh + 17][ar] = pa2.y;     \
    As[bi][akh + 18][ar] = pa2.z; As[bi][akh + 19][ar] = pa2.w;     \
    As[bi][akh + 20][ar] = pa3.x; As[bi][akh + 21][ar] = pa3.y;     \
    As[bi][akh + 22][ar] = pa3.z; As[bi][akh + 23][ar] = pa3.w;     \
    *reinterpret_cast<float4*>(&Bs[bi][bk][bc4]) = pb0;             \
    *reinterpret_cast<float4*>(&Bs[bi][bk][bc4 + 64]) = pb1;        \
    *reinterpret_cast<float4*>(&Bs[bi][bk + 16][bc4]) = pb2;        \
    *reinterpret_cast<float4*>(&Bs[bi][bk + 16][bc4 + 64]) = pb3;   \
  } while (0)

#define K1_LOAD(koff)                                                        \
  do {                                                                       \
    pa0 = *reinterpret_cast<const float4*>(Ap + (koff));                     \
    pa1 = *reinterpret_cast<const float4*>(Ap + (koff) + 4);                 \
    pa2 = *reinterpret_cast<const float4*>(Ap + (koff) + 16);                \
    pa3 = *reinterpret_cast<const float4*>(Ap + (koff) + 20);                \
    pb0 = *reinterpret_cast<const float4*>(Bp + (size_t)(koff) * DDIM);      \
    pb1 = *reinterpret_cast<const float4*>(Bp + (size_t)(koff) * DDIM + 64); \
    pb2 = *reinterpret_cast<const float4*>(Bp + (size_t)((koff) + 16) * DDIM);      \
    pb3 = *reinterpret_cast<const float4*>(Bp + (size_t)((koff) + 16) * DDIM + 64); \
  } while (0)

__global__ __launch_bounds__(256, 2)
void k1_mfma(const float* __restrict__ A, const float* __restrict__ B,
             float* __restrict__ C) {
  const int sel = probe_sel();
  if (sel >= 4) return;
  __shared__ float As[2][32][144];
  __shared__ float Bs[2][32][144];
  const int tid = threadIdx.x;
  const int lin = blockIdx.y * 8 + blockIdx.x;          // 512 blocks
  const int nlin = (lin & 7) * 64 + (lin >> 3);         // bijective XCD swizzle
  const int brow = (nlin >> 3) << 7;
  const int bcol = (nlin & 7) << 7;
  const int lane = tid & 63, w = tid >> 6;
  const int wr = w >> 1, wc = w & 1;
  const int lr = lane & 15, lg = lane >> 4;
  const int ar = tid >> 1, akh = (tid & 1) << 3;
  const int bk = tid >> 4, bc4 = (tid & 15) << 2;

  f64x4 acc[4][4];
#pragma unroll
  for (int mi = 0; mi < 4; ++mi)
#pragma unroll
    for (int nj = 0; nj < 4; ++nj)
      acc[mi][nj] = (f64x4){0.0, 0.0, 0.0, 0.0};

  const float* Ap = &A[(size_t)(brow + ar) * DDIM + akh];
  const float* Bp = &B[(size_t)bk * DDIM + bcol + bc4];

  float4 pa0, pa1, pa2, pa3, pb0, pb1, pb2, pb3;
  K1_LOAD(0);
  K1_STAGE(0);
  K1_LOAD(32);

  for (int t = 0; t < 32; ++t) {
    __syncthreads();
    const int cur = t & 1;
    if (t < 31) {
      K1_STAGE(cur ^ 1);
      if (t < 30) K1_LOAD((size_t)(t + 2) << 5);
    }
    __builtin_amdgcn_s_setprio(1);
#pragma unroll
    for (int kp = 0; kp < 8; ++kp) {
      const int ka = (kp << 2) + lg;
      double a[4], b[4];
#pragma unroll
      for (int mi = 0; mi < 4; ++mi)
        a[mi] = (double)As[cur][ka][(wr << 6) + (mi << 4) + lr];
#pragma unroll
      for (int nj = 0; nj < 4; ++nj)
        b[nj] = (double)Bs[cur][ka][(wc << 6) + (nj << 4) + lr];
#pragma unroll
      for (int mi = 0; mi < 4; ++mi)
#pragma unroll
        for (int nj = 0; nj < 4; ++nj)
          acc[mi][nj] = __builtin_amdgcn_mfma_f64_16x16x4f64(
              a[mi], b[nj], acc[mi][nj], 0, 0, 0);
    }
    __builtin_amdgcn_s_setprio(0);
  }
#pragma unroll
  for (int mi = 0; mi < 4; ++mi)
#pragma unroll
    for (int nj = 0; nj < 4; ++nj)
#pragma unroll
      for (int rg = 0; rg < 4; ++rg) {
        int ri, ci;
        dmap(sel, lg, lr, rg, ri, ci);
        C[(size_t)(brow + (wr << 6) + (mi << 4) + ri) * DDIM +
          bcol + (wc << 6) + (nj << 4) + ci] = (float)acc[mi][nj][rg];
      }
}

// ---------------------------------------------------------------------------
// k1_repair: proven vector-f64 chain kernel; runs only if layout unknown. -- UNCHANGED
// ---------------------------------------------------------------------------
__global__ __launch_bounds__(256, 2)
void k1_repair(const float* __restrict__ A, const float* __restrict__ B,
               float* __restrict__ C) {
  if (probe_sel() < 4) return;
  __shared__ double As[128][17];
  __shared__ double Bs[16][130];
  const int tid = threadIdx.x;
  const int lin = blockIdx.y * 8 + blockIdx.x;
  const int nlin = (lin & 7) * 64 + (lin >> 3);
  const int brow = (nlin >> 3) << 7;
  const int bcol = (nlin & 7) << 7;
  const int tx = tid & 15, ty = tid >> 4;
  const int ar = tid >> 1, aks = (tid & 1) << 3;
  const int bk = tid >> 4, btx = tid & 15;

  double acc[8][8];
#pragma unroll
  for (int i = 0; i < 8; ++i)
#pragma unroll
    for (int j = 0; j < 8; ++j) acc[i][j] = 0.0;

  const float* Aptr = &A[(size_t)(brow + ar) * DDIM + aks];
  const float* Bptr = &B[(size_t)bk * DDIM + bcol + (btx << 1)];

  float4 pa0, pa1;
  float2 pb[4];
  pa0 = *reinterpret_cast<const float4*>(Aptr);
  pa1 = *reinterpret_cast<const float4*>(Aptr + 4);
#pragma unroll
  for (int w = 0; w < 4; ++w)
    pb[w] = *reinterpret_cast<const float2*>(Bptr + (w << 5));

  for (int k0 = 0; k0 < DDIM; k0 += 16) {
    __syncthreads();
    As[ar][aks + 0] = (double)pa0.x; As[ar][aks + 1] = (double)pa0.y;
    As[ar][aks + 2] = (double)pa0.z; As[ar][aks + 3] = (double)pa0.w;
    As[ar][aks + 4] = (double)pa1.x; As[ar][aks + 5] = (double)pa1.y;
    As[ar][aks + 6] = (double)pa1.z; As[ar][aks + 7] = (double)pa1.w;
#pragma unroll
    for (int w = 0; w < 4; ++w) {
      Bs[bk][(btx << 1) + (w << 5) + 0] = (double)pb[w].x;
      Bs[bk][(btx << 1) + (w << 5) + 1] = (double)pb[w].y;
    }
    __syncthreads();
    if (k0 + 16 < DDIM) {
      pa0 = *reinterpret_cast<const float4*>(Aptr + k0 + 16);
      pa1 = *reinterpret_cast<const float4*>(Aptr + k0 + 20);
#pragma unroll
      for (int w = 0; w < 4; ++w)
        pb[w] = *reinterpret_cast<const float2*>(
            Bptr + (size_t)(k0 + 16) * DDIM + (w << 5));
    }
#pragma unroll 8
    for (int kk = 0; kk < 16; ++kk) {
      double a[8];
      double2 b[4];
#pragma unroll
      for (int i = 0; i < 8; ++i) a[i] = As[(ty << 3) + i][kk];
#pragma unroll
      for (int jj = 0; jj < 4; ++jj)
        b[jj] = *reinterpret_cast<const double2*>(&Bs[kk][(tx << 1) + (jj << 5)]);
#pragma unroll
      for (int i = 0; i < 8; ++i) {
#pragma unroll
        for (int jj = 0; jj < 4; ++jj) {
          acc[i][(jj << 1) + 0] = fma(a[i], b[jj].x, acc[i][(jj << 1) + 0]);
          acc[i][(jj << 1) + 1] = fma(a[i], b[jj].y, acc[i][(jj << 1) + 1]);
        }
      }
    }
  }
#pragma unroll
  for (int i = 0; i < 8; ++i) {
    float* crow = &C[(size_t)(brow + (ty << 3) + i) * DDIM + bcol + (tx << 1)];
#pragma unroll
    for (int jj = 0; jj < 4; ++jj) {
      float2 v = make_float2((float)acc[i][(jj << 1)],
                             (float)acc[i][(jj << 1) + 1]);
      *reinterpret_cast<float2*>(crow + (jj << 5)) = v;
    }
  }
}

// ---------------------------------------------------------------------------
// k2_mfma: approx scores, NOW 128x128 tile, 256 threads (4 waves 2x2), dbuf
// staging, chunked XCD swizzle, grid 1024 => 2 independent blocks/CU (LDS
// 64 KB). Epilogue: 2 phases x 64 rows, quarter-scan + ordered merge (R8
// proven). cand: 16 col-blocks x 8 = 128 slots/row.
// ---------------------------------------------------------------------------
#define K2_LOAD(koff)                                                         \
  do {                                                                        \
    _Pragma("unroll")                                                         \
    for (int q = 0; q < 4; ++q) {                                             \
      const int c = (q << 8) + tid;                                           \
      const int row = c >> 3;                                                 \
      const int gs = (c & 7) ^ (row & 7);                                     \
      const float* sT = &T[(size_t)(row0g + row) * DDIM + (koff) + (gs << 3)];\
      rT[2 * q] = *reinterpret_cast<const float4*>(sT);                       \
      rT[2 * q + 1] = *reinterpret_cast<const float4*>(sT + 4);               \
      const float* sH = &H[(size_t)(col0g + row) * DDIM + (koff) + (gs << 3)];\
      rH[2 * q] = *reinterpret_cast<const float4*>(sH);                       \
      rH[2 * q + 1] = *reinterpret_cast<const float4*>(sH + 4);               \
    }                                                                         \
  } while (0)

#define K2_STAGE(bi)                                                          \
  do {                                                                        \
    _Pragma("unroll")                                                         \
    for (int q = 0; q < 4; ++q) {                                             \
      const int c = (q << 8) + tid;                                           \
      uint4 o;                                                                \
      o.x = pkbf(rT[2 * q].x, rT[2 * q].y);                                   \
      o.y = pkbf(rT[2 * q].z, rT[2 * q].w);                                   \
      o.z = pkbf(rT[2 * q + 1].x, rT[2 * q + 1].y);                           \
      o.w = pkbf(rT[2 * q + 1].z, rT[2 * q + 1].w);                           \
      *reinterpret_cast<uint4*>(&u.stage[bi][0][c << 3]) = o;                 \
      uint4 o2;                                                               \
      o2.x = pkbf(rH[2 * q].x, rH[2 * q].y);                                  \
      o2.y = pkbf(rH[2 * q].z, rH[2 * q].w);                                  \
      o2.z = pkbf(rH[2 * q + 1].x, rH[2 * q + 1].y);                          \
      o2.w = pkbf(rH[2 * q + 1].z, rH[2 * q + 1].w);                          \
      *reinterpret_cast<uint4*>(&u.stage[bi][1][c << 3]) = o2;                \
    }                                                                         \
  } while (0)

__global__ __launch_bounds__(256, 2)
void k2_mfma(const float* __restrict__ T, const float* __restrict__ H,
             unsigned short* __restrict__ cand_v,
             unsigned char* __restrict__ cand_i) {
  __shared__ union {
    unsigned short stage[2][2][128 * 64];   // 64 KB (dbuf x {T,H})
    float Sl[64][132];                      // 33.8 KB
    struct {
      float mv[256][8];
      unsigned char mi[256][8];
    } mg;
  } u;
  const int tid = threadIdx.x;
  const int lane = tid & 63;
  const int w = tid >> 6;               // 0..3
  const int wr = w >> 1, wc = w & 1;    // 2 x 2 wave grid
  const int lr = lane & 15, lg = lane >> 4;
  // chunked XCD swizzle (1024 blocks, 1024%8==0, bijective)
  const int lin = blockIdx.z * 256 + blockIdx.y * 16 + blockIdx.x;
  const int nl = (lin & 7) * 128 + (lin >> 3);
  const int bx = nl & 15;               // col block 0..15
  const int by = (nl >> 4) & 15;        // row block 0..15
  const int z = nl >> 8;                // batch 0..3
  const int brow = by << 7, bcol = bx << 7;
  const int row0g = z * SEQ + brow;
  const int col0g = z * SEQ + bcol;

  f32x4 acc[4][4];
#pragma unroll
  for (int mi = 0; mi < 4; ++mi)
#pragma unroll
    for (int nj = 0; nj < 4; ++nj)
      acc[mi][nj] = (f32x4){0.f, 0.f, 0.f, 0.f};

  float4 rT[8], rH[8];
  K2_LOAD(0);
  K2_STAGE(0);
  K2_LOAD(64);

  for (int t = 0; t < 16; ++t) {
    __syncthreads();
    const int cur = t & 1;
    if (t < 15) {
      K2_STAGE(cur ^ 1);
      if (t < 14) K2_LOAD((t + 2) << 6);
    }
#pragma unroll
    for (int kh2 = 0; kh2 < 2; ++kh2) {
      const int sl = (kh2 << 2) + lg;
      bf16x8 bfv[4];
#pragma unroll
      for (int nj = 0; nj < 4; ++nj) {
        const int rb = (wc << 6) + (nj << 4) + lr;
        bfv[nj] = *reinterpret_cast<const bf16x8*>(
            &u.stage[cur][1][(rb << 6) + ((sl ^ (rb & 7)) << 3)]);
      }
#pragma unroll
      for (int mi = 0; mi < 4; ++mi) {
        const int ra = (wr << 6) + (mi << 4) + lr;
        const bf16x8 af = *reinterpret_cast<const bf16x8*>(
            &u.stage[cur][0][(ra << 6) + ((sl ^ (ra & 7)) << 3)]);
#pragma unroll
        for (int nj = 0; nj < 4; ++nj)
          acc[mi][nj] = __builtin_amdgcn_mfma_f32_16x16x32_bf16(
              af, bfv[nj], acc[mi][nj], 0, 0, 0);
      }
    }
  }

  // epilogue: 2 phases of 64 rows; 4 threads/row scan 32 cols; ordered merge
  const int srow = tid >> 2;     // 0..63
  const int qd = tid & 3;        // quarter (32 cols each)
#pragma unroll
  for (int p = 0; p < 2; ++p) {
    __syncthreads();
    if (wr == p) {
#pragma unroll
      for (int mi = 0; mi < 4; ++mi)
#pragma unroll
        for (int nj = 0; nj < 4; ++nj)
#pragma unroll
          for (int rg = 0; rg < 4; ++rg)
            u.Sl[(mi << 4) + (lg << 2) + rg][(wc << 6) + (nj << 4) + lr] =
                acc[mi][nj][rg];
    }
    __syncthreads();
    float v[KSEL];
    int ci[KSEL];
#pragma unroll
    for (int s = 0; s < KSEL; ++s) { v[s] = -3.0e38f; ci[s] = 0; }
    const int c0 = qd << 5;
    for (int c = 0; c < 32; ++c) {
      const float x = u.Sl[srow][c0 + c];
      if (x > v[KSEL - 1]) {
        float pv = x; int pc = c0 + c;
#pragma unroll
        for (int s = 0; s < KSEL; ++s) {
          if (x > v[s]) {
            const float tv = v[s]; const int tc = ci[s];
            v[s] = pv; ci[s] = pc; pv = tv; pc = tc;
          }
        }
      }
    }
    __syncthreads();   // all Sl reads done before mg overlay
#pragma unroll
    for (int s = 0; s < KSEL; ++s) {
      u.mg.mv[tid][s] = v[s];
      u.mg.mi[tid][s] = (unsigned char)ci[s];
    }
    __syncthreads();
    if (qd == 0) {
      // merge 4 quarter-lists in col-ascending order; strict > insertion
      // reproduces the (value desc, col asc) order of a full 0..127 scan.
      float fv[KSEL];
      int fi[KSEL];
#pragma unroll
      for (int s = 0; s < KSEL; ++s) { fv[s] = -3.0e38f; fi[s] = 0; }
#pragma unroll
      for (int t2 = 0; t2 < 4; ++t2) {
#pragma unroll
        for (int s = 0; s < KSEL; ++s) {
          const float x = u.mg.mv[tid + t2][s];
          const int idx = u.mg.mi[tid + t2][s];
          if (x > fv[KSEL - 1]) {
            float pv = x; int pc = idx;
#pragma unroll
            for (int s2 = 0; s2 < KSEL; ++s2) {
              if (x > fv[s2]) {
                const float tv = fv[s2]; const int tc = fi[s2];
                fv[s2] = pv; fi[s2] = pc; pv = tv; pc = tc;
              }
            }
          }
        }
      }
      const size_t base =
          (size_t)(row0g + (p << 6) + srow) * 128 + ((size_t)bx << 3);
#pragma unroll
      for (int s = 0; s < KSEL; ++s) {
        cand_v[base + s] = f2bf(fv[s]);
        cand_i[base + s] = (unsigned char)fi[s];
      }
    }
  }
}

// ---------------------------------------------------------------------------
// kr_rescore: extraction of approx-top-12 from 128 cands (2/lane sorted, R2
// proven) + exact f64 rescore split over 2 waves/row + stable top-8 merge.
// ---------------------------------------------------------------------------
__global__ __launch_bounds__(256)
void kr_rescore(const float* __restrict__ T, const float* __restrict__ H,
                const unsigned short* __restrict__ cand_v,
                const unsigned char* __restrict__ cand_i,
                int* __restrict__ topi, float* __restrict__ topw,
                int* __restrict__ cnt) {
  __shared__ float smv[2][2][KSEL];
  __shared__ int smi[2][2][KSEL];
  const int tid = threadIdx.x, lane = tid & 63, w = tid >> 6;
  const int rl = w >> 1;          // row slot in block: 0..1
  const int half = w & 1;         // candidate half: 0..1
  const int r = blockIdx.x * 2 + rl;
  const int b = r >> 11, iloc = r & (SEQ - 1);

  // --- extraction: 128 candidates, 2 per lane (sorted), NCAND rounds ---
  const size_t cbase = (size_t)r * 128;
  const int s0 = lane << 1, s1 = s0 + 1;
  float v0 = bf2f(cand_v[cbase + s0]);
  float v1 = bf2f(cand_v[cbase + s1]);
  int i0 = ((s0 >> 3) << 7) + cand_i[cbase + s0];
  int i1 = ((s1 >> 3) << 7) + cand_i[cbase + s1];
  if (v1 > v0) {
    const float tv = v0; v0 = v1; v1 = tv;
    const int ti = i0; i0 = i1; i1 = ti;
  }
  int keep = 0;
  for (int rnd = 0; rnd < NCAND; ++rnd) {
    float m = v0;
#pragma unroll
    for (int off = 32; off >= 1; off >>= 1) m = fmaxf(m, __shfl_xor(m, off));
    const unsigned long long bm = __ballot(v0 == m);
    const int owner = __ffsll(bm) - 1;
    const int oi = __shfl(i0, owner);
    if (lane == owner) { v0 = v1; i0 = i1; v1 = -3.0e38f; }
    if (lane == rnd) keep = oi;
  }

  // --- exact rescore of this wave's half (R10-proven full-wave dot) ---
  const float* Trow = T + (size_t)r * DDIM;
  float4 t4[4];
#pragma unroll
  for (int q = 0; q < 4; ++q)
    t4[q] = *reinterpret_cast<const float4*>(&Trow[(q << 8) + (lane << 2)]);

  float t8v[KSEL];
  int t8i[KSEL];
#pragma unroll
  for (int p = 0; p < KSEL; ++p) { t8v[p] = -1.0f; t8i[p] = IMAXC; }

  const int c0 = half * (NCAND / 2);
  for (int c = c0; c < c0 + NCAND / 2; ++c) {
    const int j = __shfl(keep, c);
    const float* Hrow = H + ((size_t)(b << 11) + j) * DDIM;
    double s = 0.0;
#pragma unroll
    for (int q = 0; q < 4; ++q) {
      const float4 h = *reinterpret_cast<const float4*>(&Hrow[(q << 8) + (lane << 2)]);
      s = fma((double)t4[q].x, (double)h.x, s);
      s = fma((double)t4[q].y, (double)h.y, s);
      s = fma((double)t4[q].z, (double)h.z, s);
      s = fma((double)t4[q].w, (double)h.w, s);
    }
#pragma unroll
    for (int off = 1; off < 64; off <<= 1) s += __shfl_xor(s, off);
    const float aff = expf((float)s);
    const bool g7 = (aff > t8v[KSEL - 1]) ||
                    (aff == t8v[KSEL - 1] && j < t8i[KSEL - 1]);
    if (g7) {
      float pv = aff; int pi = j;
#pragma unroll
      for (int p = 0; p < KSEL; ++p) {
        const bool g = (aff > t8v[p]) || (aff == t8v[p] && j < t8i[p]);
        if (g) {
          const float tv = t8v[p]; const int ti = t8i[p];
          t8v[p] = pv; t8i[p] = pi; pv = tv; pi = ti;
        }
      }
    }
  }

  if (lane == 0) {
#pragma unroll
    for (int p = 0; p < KSEL; ++p) {
      smv[rl][half][p] = t8v[p];
      smi[rl][half][p] = t8i[p];
    }
  }
  __syncthreads();
  if (half == 0 && lane == 0) {
#pragma unroll
    for (int p = 0; p < KSEL; ++p) {
      const float x = smv[rl][1][p];
      const int jx = smi[rl][1][p];
      const bool g7 = (x > t8v[KSEL - 1]) ||
                      (x == t8v[KSEL - 1] && jx < t8i[KSEL - 1]);
      if (g7) {
        float pv = x; int pi = jx;
#pragma unroll
        for (int q = 0; q < KSEL; ++q) {
          const bool g = (x > t8v[q]) || (x == t8v[q] && jx < t8i[q]);
          if (g) {
            const float tv = t8v[q]; const int ti = t8i[q];
            t8v[q] = pv; t8i[q] = pi; pv = tv; pi = ti;
          }
        }
      }
    }
    float sum = 0.0f;
#pragma unroll
    for (int p = 0; p < KSEL; ++p) sum += t8v[p];
    sum += 1e-8f;
    int c8 = KSEL;
#pragma unroll
    for (int p = 0; p < KSEL; ++p)
      if (t8i[p] == iloc) --c8;
    cnt[r] = c8;
#pragma unroll
    for (int p = 0; p < KSEL; ++p) {
      topi[(size_t)r * KSEL + p] = t8i[p];
      topw[(size_t)r * KSEL + p] = t8v[p] / sum;
    }
  }
}

// ---------------------------------------------------------------------------
// k4_scan / k5_emit -- UNCHANGED
// ---------------------------------------------------------------------------
__global__ __launch_bounds__(1024)
void k4_scan(const int* __restrict__ cnt, int* __restrict__ off) {
  __shared__ int part[1024];
  const int t = threadIdx.x;
  int loc[8];
  int s = 0;
#pragma unroll
  for (int i = 0; i < 8; ++i) { loc[i] = s; s += cnt[t * 8 + i]; }
  part[t] = s;
  __syncthreads();
  for (int d = 1; d < 1024; d <<= 1) {
    const int add = (t >= d) ? part[t - d] : 0;
    __syncthreads();
    part[t] += add;
    __syncthreads();
  }
  const int base = (t == 0) ? 0 : part[t - 1];
#pragma unroll
  for (int i = 0; i < 8; ++i) off[t * 8 + i] = base + loc[i];
}

__global__ __launch_bounds__(256)
void k5_emit(const int* __restrict__ topi, const float* __restrict__ topw,
             const int* __restrict__ off, float* __restrict__ out, int E) {
  const int r = blockIdx.x * 256 + threadIdx.x;
  if (r >= NROWS) return;
  const int o = off[r];
  const int sloc = r & (SEQ - 1);
  const int bbase = r & ~(SEQ - 1);
  int e = 0;
#pragma unroll
  for (int p = 0; p < KSEL; ++p) {
    const int id = topi[(size_t)r * KSEL + p];
    const float w = topw[(size_t)r * KSEL + p];
    if (id != sloc) {
      const int pos = o + e;
      if (pos < E) {
        out[pos] = (float)r;
        out[(size_t)E + pos] = (float)(bbase + id);
        out[2 * (size_t)E + pos] = w;
      }
      ++e;
    }
  }
}

// ---------------------------------------------------------------------------
extern "C" void kernel_launch(void* const* d_in, const int* in_sizes, int n_in,
                              void* d_out, int out_size, void* d_ws,
                              size_t ws_size, hipStream_t stream) {
  const float* H = (const float*)d_in[0];      // [4,2048,1024]
  const float* Wphi = (const float*)d_in[1];   // [1024,1024]
  const float* Wpsi = (const float*)d_in[2];   // [1024,1024]
  float* out = (float*)d_out;
  const int E = out_size / 3;

  char* base = (char*)d_ws;
  float* T = (float*)base;                         // 32 MB
  char* regionX = base + 33554432;                 // 4 MB shared region
  float* Wc = (float*)regionX;                     //   Wc (dead after k1)
  unsigned short* cand_v = (unsigned short*)regionX;           // 2 MB used
  unsigned char* cand_i = (unsigned char*)(regionX + 2097152); // 1 MB used
  char* pp = regionX + 4194304;
  int* topi = (int*)pp;  pp += 262144;
  float* topw = (float*)pp; pp += 262144;
  int* cnt = (int*)pp;   pp += 32768;
  int* off = (int*)pp;   pp += 32768;   // pp now at base+38338560

  // split-K partials: 4 x 8 MB f64 at base+38338560 .. base+71892992
  double* Wp = (double*)(base + 38338560);
  const size_t NEED_SPLITK = 71892992;  // R13 proved ws >= 72.35 MB
  const bool splitk = (ws_size >= NEED_SPLITK);

  // Wc = Wphi^T * Wpsi  (f64 MFMA; split-K if ws allows; vector repair if
  // layout unknown — all kernels self-probe the D layout)
  if (splitk) {
    k0s_mfma<<<dim3(16, 16, 4), 256, 0, stream>>>(Wphi, Wpsi, Wp);
    k0red<<<dim3(2048), 256, 0, stream>>>(Wp, Wc);
  } else {
    k0_mfma<<<dim3(16, 16), 256, 0, stream>>>(Wphi, Wpsi, Wc);
  }
  k0_repair<<<dim3(16, 16), 256, 0, stream>>>(Wphi, Wpsi, Wc);
  // T = H * Wc  (f64 MFMA, BK=32 dbuf + setprio; vector repair if unknown)
  k1_mfma<<<dim3(8, 64), 256, 0, stream>>>(H, Wc, T);
  k1_repair<<<dim3(8, 64), 256, 0, stream>>>(H, Wc, T);
  // approx MFMA scores, 128^2 tile, dbuf staging, 2 blocks/CU, XCD swizzle
  k2_mfma<<<dim3(16, 16, 4), 256, 0, stream>>>(T, H, cand_v, cand_i);
  // extraction + exact f64 rescore (2 waves/row) + stable top-8 + counts
  kr_rescore<<<dim3(NROWS / 2), 256, 0, stream>>>(T, H, cand_v, cand_i,
                                                  topi, topw, cnt);
  // prefix scan + emit
  k4_scan<<<dim3(1), 1024, 0, stream>>>(cnt, off);
  k5_emit<<<dim3(NROWS / 256), 256, 0, stream>>>(topi, topw, off, out, E);
}